// Round 1
// baseline (1649.737 us; speedup 1.0000x reference)
//
#include <hip/hip_runtime.h>
#include <math.h>

#define LN_EPS 1e-5f

__device__ __forceinline__ float sigmoidf(float x) { return 1.0f / (1.0f + expf(-x)); }

__device__ __forceinline__ float wave_sum(float v) {
    v += __shfl_xor(v, 32, 64);
    v += __shfl_xor(v, 16, 64);
    v += __shfl_xor(v, 8, 64);
    v += __shfl_xor(v, 4, 64);
    v += __shfl_xor(v, 2, 64);
    v += __shfl_xor(v, 1, 64);
    return v;
}

// ---------------------------------------------------------------------------
// Lateral 1x1 conv + BatchNorm(eval) + NCHW->(B,N,C) transpose into flat.
// Grid: (HW/32, B), block 256. Tile: 32 pixels x 256 out-channels.
// Thread (tr = tid>>6, tc = tid&63) owns 8 pixels x 4 out-channels.
// ---------------------------------------------------------------------------
__global__ __launch_bounds__(256) void lateral_kernel(
    const float* __restrict__ x,     // [B, Cin, HW]
    const float* __restrict__ Wlat,  // [256, Cin]  (o-major)
    const float* __restrict__ bng, const float* __restrict__ bnb,
    const float* __restrict__ bnm, const float* __restrict__ bnv,
    float* __restrict__ flat,        // [B, 5376, 256]
    int Cin, int HW, int base)
{
    __shared__ float sw[32 * 260];   // [kk][o], padded stride
    __shared__ float sx[32 * 36];    // [kk][m], padded stride

    const int t  = threadIdx.x;
    const int tr = t >> 6;           // wave id 0..3 -> pixel group
    const int tc = t & 63;           // lane -> out-channel group
    const int p0 = blockIdx.x * 32;
    const int b  = blockIdx.y;
    const float* xb = x + (size_t)b * Cin * HW;

    float acc[8][4];
#pragma unroll
    for (int i = 0; i < 8; i++)
#pragma unroll
        for (int j = 0; j < 4; j++) acc[i][j] = 0.0f;

    for (int kc = 0; kc < Cin; kc += 32) {
        // stage W chunk transposed: sw[kk][o] = Wlat[o*Cin + kc+kk]
#pragma unroll
        for (int it = 0; it < 32; ++it) {
            int idx = it * 256 + t;
            int o = idx >> 5, kk = idx & 31;
            sw[kk * 260 + o] = Wlat[o * Cin + kc + kk];
        }
        // stage x chunk: sx[kk][m] = xb[(kc+kk)*HW + p0+m]
#pragma unroll
        for (int it = 0; it < 4; ++it) {
            int idx = it * 256 + t;
            int kk = idx >> 5, m = idx & 31;
            sx[kk * 36 + m] = xb[(size_t)(kc + kk) * HW + p0 + m];
        }
        __syncthreads();
#pragma unroll 8
        for (int kk = 0; kk < 32; ++kk) {
            const float4 wv = *(const float4*)&sw[kk * 260 + tc * 4];
            const float4 x0 = *(const float4*)&sx[kk * 36 + tr * 8];
            const float4 x1 = *(const float4*)&sx[kk * 36 + tr * 8 + 4];
            const float xv[8] = {x0.x, x0.y, x0.z, x0.w, x1.x, x1.y, x1.z, x1.w};
#pragma unroll
            for (int mi = 0; mi < 8; mi++) {
                acc[mi][0] += xv[mi] * wv.x;
                acc[mi][1] += xv[mi] * wv.y;
                acc[mi][2] += xv[mi] * wv.z;
                acc[mi][3] += xv[mi] * wv.w;
            }
        }
        __syncthreads();
    }

    const int o = tc * 4;
    const float4 gg = *(const float4*)&bng[o];
    const float4 bb = *(const float4*)&bnb[o];
    const float4 mm = *(const float4*)&bnm[o];
    const float4 vv = *(const float4*)&bnv[o];
    float sc[4], mh[4], bh[4];
    sc[0] = gg.x * rsqrtf(vv.x + LN_EPS); sc[1] = gg.y * rsqrtf(vv.y + LN_EPS);
    sc[2] = gg.z * rsqrtf(vv.z + LN_EPS); sc[3] = gg.w * rsqrtf(vv.w + LN_EPS);
    mh[0] = mm.x; mh[1] = mm.y; mh[2] = mm.z; mh[3] = mm.w;
    bh[0] = bb.x; bh[1] = bb.y; bh[2] = bb.z; bh[3] = bb.w;

#pragma unroll
    for (int mi = 0; mi < 8; mi++) {
        const int p = p0 + tr * 8 + mi;
        const size_t row = (size_t)b * 5376 + base + p;
        float4 out;
        out.x = (acc[mi][0] - mh[0]) * sc[0] + bh[0];
        out.y = (acc[mi][1] - mh[1]) * sc[1] + bh[1];
        out.z = (acc[mi][2] - mh[2]) * sc[2] + bh[2];
        out.w = (acc[mi][3] - mh[3]) * sc[3] + bh[3];
        *(float4*)&flat[row * 256 + o] = out;
    }
}

// ---------------------------------------------------------------------------
// One MLP layer: H = SiLU(LN(X @ W + bias)) for [M,256] x [256,256].
// If Wf != nullptr: fused final projection -> logits[r] = silu_row . Wf + bf
// (H not written). Grid: M/32 blocks, block 256.
// ---------------------------------------------------------------------------
__global__ __launch_bounds__(256) void mlp_layer(
    const float* __restrict__ X,     // [M, 256]
    const float* __restrict__ W,     // [256, 256] (k-major)
    const float* __restrict__ bias,  // [256]
    const float* __restrict__ lng, const float* __restrict__ lnb,
    float* __restrict__ H,           // [M, 256] (unused in fused mode)
    const float* __restrict__ Wf,    // [256] or nullptr
    const float* __restrict__ bfp,   // [1] or nullptr
    float* __restrict__ logits)      // [M] (fused mode only)
{
    __shared__ float sw[32 * 256];   // [kk][o]
    __shared__ float sx[32 * 36];    // [kk][m], padded

    const int t  = threadIdx.x;
    const int tr = t >> 6;
    const int tc = t & 63;
    const int r0 = blockIdx.x * 32;

    float acc[8][4];
#pragma unroll
    for (int i = 0; i < 8; i++)
#pragma unroll
        for (int j = 0; j < 4; j++) acc[i][j] = 0.0f;

    for (int kc = 0; kc < 256; kc += 32) {
#pragma unroll
        for (int it = 0; it < 32; ++it)
            sw[it * 256 + t] = W[(kc + it) * 256 + t];
#pragma unroll
        for (int it = 0; it < 4; ++it) {
            int idx = it * 256 + t;
            int m = idx >> 5, kk = idx & 31;
            sx[kk * 36 + m] = X[(size_t)(r0 + m) * 256 + kc + kk];
        }
        __syncthreads();
#pragma unroll 8
        for (int kk = 0; kk < 32; ++kk) {
            const float4 wv = *(const float4*)&sw[kk * 256 + tc * 4];
            const float4 x0 = *(const float4*)&sx[kk * 36 + tr * 8];
            const float4 x1 = *(const float4*)&sx[kk * 36 + tr * 8 + 4];
            const float xv[8] = {x0.x, x0.y, x0.z, x0.w, x1.x, x1.y, x1.z, x1.w};
#pragma unroll
            for (int mi = 0; mi < 8; mi++) {
                acc[mi][0] += xv[mi] * wv.x;
                acc[mi][1] += xv[mi] * wv.y;
                acc[mi][2] += xv[mi] * wv.z;
                acc[mi][3] += xv[mi] * wv.w;
            }
        }
        __syncthreads();
    }

    const int o = tc * 4;
    const float4 bv = *(const float4*)&bias[o];
    const float4 gv = *(const float4*)&lng[o];
    const float4 betav = *(const float4*)&lnb[o];

    // add bias, per-row LayerNorm stats across the wave (wave tr owns rows tr*8..tr*8+7 fully)
#pragma unroll
    for (int mi = 0; mi < 8; mi++) {
        acc[mi][0] += bv.x; acc[mi][1] += bv.y; acc[mi][2] += bv.z; acc[mi][3] += bv.w;
    }
    float mean[8], rstd[8];
#pragma unroll
    for (int mi = 0; mi < 8; mi++) {
        float s  = acc[mi][0] + acc[mi][1] + acc[mi][2] + acc[mi][3];
        float ss = acc[mi][0] * acc[mi][0] + acc[mi][1] * acc[mi][1] +
                   acc[mi][2] * acc[mi][2] + acc[mi][3] * acc[mi][3];
        s  = wave_sum(s);
        ss = wave_sum(ss);
        const float m = s * (1.0f / 256.0f);
        const float var = ss * (1.0f / 256.0f) - m * m;
        mean[mi] = m;
        rstd[mi] = rsqrtf(var + LN_EPS);
    }

    const float glv[4] = {gv.x, gv.y, gv.z, gv.w};
    const float blv[4] = {betav.x, betav.y, betav.z, betav.w};

    if (Wf == nullptr) {
#pragma unroll
        for (int mi = 0; mi < 8; mi++) {
            float4 out;
            float v0 = (acc[mi][0] - mean[mi]) * rstd[mi] * glv[0] + blv[0];
            float v1 = (acc[mi][1] - mean[mi]) * rstd[mi] * glv[1] + blv[1];
            float v2 = (acc[mi][2] - mean[mi]) * rstd[mi] * glv[2] + blv[2];
            float v3 = (acc[mi][3] - mean[mi]) * rstd[mi] * glv[3] + blv[3];
            out.x = v0 * sigmoidf(v0);
            out.y = v1 * sigmoidf(v1);
            out.z = v2 * sigmoidf(v2);
            out.w = v3 * sigmoidf(v3);
            *(float4*)&H[(size_t)(r0 + tr * 8 + mi) * 256 + o] = out;
        }
    } else {
        const float4 wfv = *(const float4*)&Wf[o];
        const float wfl[4] = {wfv.x, wfv.y, wfv.z, wfv.w};
        const float bf0 = bfp[0];
#pragma unroll
        for (int mi = 0; mi < 8; mi++) {
            float p = 0.0f;
#pragma unroll
            for (int j = 0; j < 4; j++) {
                float v = (acc[mi][j] - mean[mi]) * rstd[mi] * glv[j] + blv[j];
                v = v * sigmoidf(v);
                p += v * wfl[j];
            }
            p = wave_sum(p);
            if (tc == 0) logits[r0 + tr * 8 + mi] = p + bf0;
        }
    }
}

// ---------------------------------------------------------------------------
// Top-100 selection per batch (sorted desc, stable ties -> lower index),
// writes scores + num_instances to d_out and indices to ws.
// Grid: B blocks, block 256.
// ---------------------------------------------------------------------------
__global__ __launch_bounds__(256) void topk_kernel(
    const float* __restrict__ logits,  // [B, 5376]
    int* __restrict__ idx_out,         // [B*100]
    float* __restrict__ out,           // d_out
    int B)
{
    __shared__ float v[5376];
    __shared__ float wv_s[4];
    __shared__ int wi_s[4];

    const int t = threadIdx.x;
    const int b = blockIdx.x;
    const int lane = t & 63, w = t >> 6;

    for (int i = t; i < 5376; i += 256) v[i] = logits[b * 5376 + i];
    __syncthreads();

    int cnt = 0;
    for (int k = 0; k < 100; k++) {
        float bv = -1e30f;
        int bi = 0x7fffffff;
        for (int i = t; i < 5376; i += 256) {
            float val = v[i];
            if (val > bv) { bv = val; bi = i; }   // ascending scan keeps lowest idx on ties
        }
#pragma unroll
        for (int off = 32; off > 0; off >>= 1) {
            float ov = __shfl_xor(bv, off, 64);
            int oi = __shfl_xor(bi, off, 64);
            if (ov > bv || (ov == bv && oi < bi)) { bv = ov; bi = oi; }
        }
        if (lane == 0) { wv_s[w] = bv; wi_s[w] = bi; }
        __syncthreads();
        if (t == 0) {
            float fb = wv_s[0]; int fi = wi_s[0];
            for (int q = 1; q < 4; q++)
                if (wv_s[q] > fb || (wv_s[q] == fb && wi_s[q] < fi)) { fb = wv_s[q]; fi = wi_s[q]; }
            v[fi] = -1e30f;
            idx_out[b * 100 + k] = fi;
            out[B + b * 100 + k] = sigmoidf(fb);
            if (fb > 0.0f) cnt++;
        }
        __syncthreads();
    }
    if (t == 0) out[b] = (float)cnt;  // num_instances
}

// gather g[r,:] = flat[b, idx[r], :]
__global__ __launch_bounds__(256) void gather_kernel(
    const float* __restrict__ flat, const int* __restrict__ idx,
    float* __restrict__ g)
{
    const int r = blockIdx.x;
    const int b = r / 100;
    const int n = idx[r];
    g[(size_t)r * 256 + threadIdx.x] = flat[((size_t)b * 5376 + n) * 256 + threadIdx.x];
}

// classes[r] = argmax_j (h[r] . Wf[:,j] + bf[j]),  j < 80
__global__ __launch_bounds__(256) void cls_final(
    const float* __restrict__ Hin, const float* __restrict__ Wf,
    const float* __restrict__ bf, float* __restrict__ out, int obase)
{
    __shared__ float h[256];
    __shared__ float lg[80];
    const int r = blockIdx.x, t = threadIdx.x;
    h[t] = Hin[(size_t)r * 256 + t];
    __syncthreads();
    if (t < 80) {
        float a = bf[t];
        for (int k = 0; k < 256; k++) a += h[k] * Wf[k * 80 + t];
        lg[t] = a;
    }
    __syncthreads();
    if (t == 0) {
        float fb = lg[0]; int fi = 0;
        for (int j = 1; j < 80; j++)
            if (lg[j] > fb) { fb = lg[j]; fi = j; }   // strict > keeps lowest idx
        out[obase + r] = (float)fi;
    }
}

// boxes[r,:] = (offsets[n] + scales[n] * exp(h[r] . Wf + bf)) * [fw,fh,fw,fh]
__global__ __launch_bounds__(256) void box_final(
    const float* __restrict__ Hin, const float* __restrict__ Wf,
    const float* __restrict__ bf, const int* __restrict__ idx,
    const int* __restrict__ full_h, const int* __restrict__ full_w,
    float* __restrict__ out, int obase)
{
    const int t = threadIdx.x;
    const int lane = t & 63, w = t >> 6;
    const int r = blockIdx.x * 4 + w;
    const float* hrow = Hin + (size_t)r * 256;

    float a0 = 0.f, a1 = 0.f, a2 = 0.f, a3 = 0.f;
    for (int k = lane; k < 256; k += 64) {
        const float hv = hrow[k];
        const float4 wf = *(const float4*)&Wf[k * 4];
        a0 += hv * wf.x; a1 += hv * wf.y; a2 += hv * wf.z; a3 += hv * wf.w;
    }
    a0 = wave_sum(a0); a1 = wave_sum(a1); a2 = wave_sum(a2); a3 = wave_sum(a3);

    if (lane == 0) {
        a0 += bf[0]; a1 += bf[1]; a2 += bf[2]; a3 += bf[3];
        const int n = idx[r];
        int base, gw, gh;
        if (n < 4096)      { base = 0;    gw = 64; gh = 64; }
        else if (n < 5120) { base = 4096; gw = 32; gh = 32; }
        else               { base = 5120; gw = 16; gh = 16; }
        const int p = n - base;
        const int py = p / gw, px = p % gw;
        const float gx = (px + 0.5f) / gw;
        const float gy = (py + 0.5f) / gh;
        const float fw = (float)full_w[0], fh = (float)full_h[0];
        out[obase + r * 4 + 0] = (gx - 0.5f / gw * expf(a0)) * fw;
        out[obase + r * 4 + 1] = (gy - 0.5f / gh * expf(a1)) * fh;
        out[obase + r * 4 + 2] = (gx + 0.5f / gw * expf(a2)) * fw;
        out[obase + r * 4 + 3] = (gy + 0.5f / gh * expf(a3)) * fh;
    }
}

extern "C" void kernel_launch(void* const* d_in, const int* in_sizes, int n_in,
                              void* d_out, int out_size, void* d_ws, size_t ws_size,
                              hipStream_t stream)
{
    const float* x3  = (const float*)d_in[0];
    const float* x4  = (const float*)d_in[1];
    const float* x5  = (const float*)d_in[2];
    const float* lw3 = (const float*)d_in[3];
    const float* lw4 = (const float*)d_in[4];
    const float* lw5 = (const float*)d_in[5];
    const float* bng = (const float*)d_in[6];
    const float* bnb = (const float*)d_in[7];
    const float* bnm = (const float*)d_in[8];
    const float* bnv = (const float*)d_in[9];

    const float* loc_Ws  = (const float*)d_in[10];
    const float* loc_bs  = (const float*)d_in[11];
    const float* loc_lng = (const float*)d_in[12];
    const float* loc_lnb = (const float*)d_in[13];
    const float* loc_Wf  = (const float*)d_in[14];
    const float* loc_bf  = (const float*)d_in[15];

    const float* cls_Ws  = (const float*)d_in[16];
    const float* cls_bs  = (const float*)d_in[17];
    const float* cls_lng = (const float*)d_in[18];
    const float* cls_lnb = (const float*)d_in[19];
    const float* cls_Wf  = (const float*)d_in[20];
    const float* cls_bf  = (const float*)d_in[21];

    const float* box_Ws  = (const float*)d_in[22];
    const float* box_bs  = (const float*)d_in[23];
    const float* box_lng = (const float*)d_in[24];
    const float* box_lnb = (const float*)d_in[25];
    const float* box_Wf  = (const float*)d_in[26];
    const float* box_bf  = (const float*)d_in[27];

    const int* full_h = (const int*)d_in[28];
    const int* full_w = (const int*)d_in[29];

    const int B = in_sizes[0] / (256 * 64 * 64);   // 8
    const int N = 5376;
    const int M = B * N;                           // 43008

    float* ws = (float*)d_ws;
    const size_t FL = (size_t)M * 256;
    float* flat = ws;
    float* bufA = ws + FL;
    float* bufB = ws + 2 * FL;
    // small buffers alias into bufB's region once the loc ping-pong is done with it
    float* loc  = bufB;                            // [M]   (written by fused layer-3; bufB free then)
    int*   idxb = (int*)(loc + M);                 // [B*100]
    float* g    = (float*)(idxb + B * 100);        // [B*100*256]
    float* h1   = g  + (size_t)B * 100 * 256;
    float* h2   = h1 + (size_t)B * 100 * 256;

    float* out = (float*)d_out;
    const int oCls = B + B * 100;
    const int oBox = B + 2 * B * 100;

    const dim3 blk(256);

    // 1) lateral conv + BN -> flat
    lateral_kernel<<<dim3(4096 / 32, B), blk, 0, stream>>>(x3, lw3, bng + 0,   bnb + 0,   bnm + 0,   bnv + 0,   flat, 256,  4096, 0);
    lateral_kernel<<<dim3(1024 / 32, B), blk, 0, stream>>>(x4, lw4, bng + 256, bnb + 256, bnm + 256, bnv + 256, flat, 512,  1024, 4096);
    lateral_kernel<<<dim3(256  / 32, B), blk, 0, stream>>>(x5, lw5, bng + 512, bnb + 512, bnm + 512, bnv + 512, flat, 1024, 256,  5120);

    // 2) loc MLP (layer 3 fuses the final 256->1 projection into loc logits)
    const int gM = M / 32;
    mlp_layer<<<gM, blk, 0, stream>>>(flat, loc_Ws + 0 * 65536, loc_bs + 0 * 256, loc_lng + 0 * 256, loc_lnb + 0 * 256, bufA, nullptr, nullptr, nullptr);
    mlp_layer<<<gM, blk, 0, stream>>>(bufA, loc_Ws + 1 * 65536, loc_bs + 1 * 256, loc_lng + 1 * 256, loc_lnb + 1 * 256, bufB, nullptr, nullptr, nullptr);
    mlp_layer<<<gM, blk, 0, stream>>>(bufB, loc_Ws + 2 * 65536, loc_bs + 2 * 256, loc_lng + 2 * 256, loc_lnb + 2 * 256, bufA, nullptr, nullptr, nullptr);
    mlp_layer<<<gM, blk, 0, stream>>>(bufA, loc_Ws + 3 * 65536, loc_bs + 3 * 256, loc_lng + 3 * 256, loc_lnb + 3 * 256, nullptr, loc_Wf, loc_bf, loc);

    // 3) top-k + scores + num_instances
    topk_kernel<<<B, blk, 0, stream>>>(loc, idxb, out, B);

    // 4) gather selected features
    gather_kernel<<<B * 100, blk, 0, stream>>>(flat, idxb, g);

    // 5) cls head
    const int gK = (B * 100) / 32;                 // 25
    mlp_layer<<<gK, blk, 0, stream>>>(g,  cls_Ws + 0 * 65536, cls_bs + 0 * 256, cls_lng + 0 * 256, cls_lnb + 0 * 256, h1, nullptr, nullptr, nullptr);
    mlp_layer<<<gK, blk, 0, stream>>>(h1, cls_Ws + 1 * 65536, cls_bs + 1 * 256, cls_lng + 1 * 256, cls_lnb + 1 * 256, h2, nullptr, nullptr, nullptr);
    mlp_layer<<<gK, blk, 0, stream>>>(h2, cls_Ws + 2 * 65536, cls_bs + 2 * 256, cls_lng + 2 * 256, cls_lnb + 2 * 256, h1, nullptr, nullptr, nullptr);
    mlp_layer<<<gK, blk, 0, stream>>>(h1, cls_Ws + 3 * 65536, cls_bs + 3 * 256, cls_lng + 3 * 256, cls_lnb + 3 * 256, h2, nullptr, nullptr, nullptr);
    cls_final<<<B * 100, blk, 0, stream>>>(h2, cls_Wf, cls_bf, out, oCls);

    // 6) box head
    mlp_layer<<<gK, blk, 0, stream>>>(g,  box_Ws + 0 * 65536, box_bs + 0 * 256, box_lng + 0 * 256, box_lnb + 0 * 256, h1, nullptr, nullptr, nullptr);
    mlp_layer<<<gK, blk, 0, stream>>>(h1, box_Ws + 1 * 65536, box_bs + 1 * 256, box_lng + 1 * 256, box_lnb + 1 * 256, h2, nullptr, nullptr, nullptr);
    mlp_layer<<<gK, blk, 0, stream>>>(h2, box_Ws + 2 * 65536, box_bs + 2 * 256, box_lng + 2 * 256, box_lnb + 2 * 256, h1, nullptr, nullptr, nullptr);
    mlp_layer<<<gK, blk, 0, stream>>>(h1, box_Ws + 3 * 65536, box_bs + 3 * 256, box_lng + 3 * 256, box_lnb + 3 * 256, h2, nullptr, nullptr, nullptr);
    box_final<<<(B * 100) / 4, blk, 0, stream>>>(h2, box_Wf, box_bf, idxb, full_h, full_w, out, oBox);
}

// Round 2
// 1113.296 us; speedup vs baseline: 1.4818x; 1.4818x over previous
//
#include <hip/hip_runtime.h>
#include <math.h>

#define LN_EPS 1e-5f

__device__ __forceinline__ float sigmoidf(float x) { return 1.0f / (1.0f + expf(-x)); }

__device__ __forceinline__ float wave_sum(float v) {
    v += __shfl_xor(v, 32, 64);
    v += __shfl_xor(v, 16, 64);
    v += __shfl_xor(v, 8, 64);
    v += __shfl_xor(v, 4, 64);
    v += __shfl_xor(v, 2, 64);
    v += __shfl_xor(v, 1, 64);
    return v;
}

// ---------------------------------------------------------------------------
// W [256][Cin] -> Wt [Cin][256]. Grid (Cin/32, 256/32), block 256.
// ---------------------------------------------------------------------------
__global__ __launch_bounds__(256) void transpose_w(
    const float* __restrict__ W, float* __restrict__ Wt, int Cin)
{
    __shared__ float T[32][33];
    const int c0 = blockIdx.x * 32, o0 = blockIdx.y * 32;
    const int t = threadIdx.x;
    const int ci = t & 31, oi = t >> 5;   // 8 o-rows per rep
#pragma unroll
    for (int rep = 0; rep < 4; rep++)
        T[oi + rep * 8][ci] = W[(size_t)(o0 + oi + rep * 8) * Cin + c0 + ci];
    __syncthreads();
    const int oi2 = t & 31, ci2 = t >> 5;
#pragma unroll
    for (int rep = 0; rep < 4; rep++)
        Wt[(size_t)(c0 + ci2 + rep * 8) * 256 + o0 + oi2] = T[oi2][ci2 + rep * 8];
}

// ---------------------------------------------------------------------------
// Lateral 1x1 conv + BN + transpose to flat, with o-split for parallelism.
// Grid (HW/PX, B, 256/OT), block 256. Wt is k-major [Cin][256].
// Thread: tc = t % (OT/4) -> 4 outs; tr = t / (OT/4) -> RPT pixels.
// ---------------------------------------------------------------------------
template<int PX, int OT, int RPT, int CHUNKS>
__global__ __launch_bounds__(256) void lateral_k(
    const float* __restrict__ x,      // [B, Cin, HW]
    const float* __restrict__ Wt,     // [Cin, 256]
    const float* __restrict__ bng, const float* __restrict__ bnb,
    const float* __restrict__ bnm, const float* __restrict__ bnv,
    float* __restrict__ flat, int HW, int base)
{
    constexpr int GO = OT / 4;
    __shared__ float Wc[32 * OT];
    __shared__ float sx[32 * PX];

    const int t  = threadIdx.x;
    const int tc = t % GO;
    const int tr = t / GO;
    const int p0 = blockIdx.x * PX;
    const int b  = blockIdx.y;
    const int o0 = blockIdx.z * OT;
    const int Cin = CHUNKS * 32;
    const float* xb = x + (size_t)b * Cin * HW;

    float acc[RPT][4];
#pragma unroll
    for (int r = 0; r < RPT; r++)
#pragma unroll
        for (int c = 0; c < 4; c++) acc[r][c] = 0.0f;

    for (int ch = 0; ch < CHUNKS; ch++) {
        const int kc = ch * 32;
        __syncthreads();
        // stage W chunk [32][OT], coalesced float4
#pragma unroll
        for (int i = 0; i < OT / 32; i++) {
            const int q = i * 256 + t;
            const int kk = q / (OT / 4), c4 = q % (OT / 4);
            *(float4*)&Wc[kk * OT + c4 * 4] =
                *(const float4*)&Wt[(size_t)(kc + kk) * 256 + o0 + c4 * 4];
        }
        // stage x chunk [32][PX], coalesced float4
        if (PX == 32 || t < 8 * PX) {
            const int q = t;
            const int kk = q / (PX / 4), c4 = q % (PX / 4);
            *(float4*)&sx[kk * PX + c4 * 4] =
                *(const float4*)&xb[(size_t)(kc + kk) * HW + p0 + c4 * 4];
        }
        __syncthreads();
#pragma unroll 8
        for (int kk = 0; kk < 32; kk++) {
            const float4 wv = *(const float4*)&Wc[kk * OT + tc * 4];
            float xv[RPT];
            if (RPT == 4) {
                const float4 xq = *(const float4*)&sx[kk * PX + tr * 4];
                xv[0] = xq.x; xv[1] = xq.y; xv[2] = xq.z; xv[3] = xq.w;
            } else if (RPT == 2) {
                const float2 xq = *(const float2*)&sx[kk * PX + tr * 2];
                xv[0] = xq.x; xv[1] = xq.y;
            } else {
                xv[0] = sx[kk * PX + tr];
            }
#pragma unroll
            for (int r = 0; r < RPT; r++) {
                acc[r][0] += xv[r] * wv.x;
                acc[r][1] += xv[r] * wv.y;
                acc[r][2] += xv[r] * wv.z;
                acc[r][3] += xv[r] * wv.w;
            }
        }
    }

    const int o = o0 + tc * 4;
    const float4 gg = *(const float4*)&bng[o];
    const float4 bb = *(const float4*)&bnb[o];
    const float4 mm = *(const float4*)&bnm[o];
    const float4 vv = *(const float4*)&bnv[o];
    const float sc[4] = {gg.x * rsqrtf(vv.x + LN_EPS), gg.y * rsqrtf(vv.y + LN_EPS),
                         gg.z * rsqrtf(vv.z + LN_EPS), gg.w * rsqrtf(vv.w + LN_EPS)};
    const float mh[4] = {mm.x, mm.y, mm.z, mm.w};
    const float bh[4] = {bb.x, bb.y, bb.z, bb.w};

#pragma unroll
    for (int r = 0; r < RPT; r++) {
        const int p = p0 + tr * RPT + r;
        const size_t row = (size_t)b * 5376 + base + p;
        float4 outv;
        outv.x = (acc[r][0] - mh[0]) * sc[0] + bh[0];
        outv.y = (acc[r][1] - mh[1]) * sc[1] + bh[1];
        outv.z = (acc[r][2] - mh[2]) * sc[2] + bh[2];
        outv.w = (acc[r][3] - mh[3]) * sc[3] + bh[3];
        *(float4*)&flat[row * 256 + o] = outv;
    }
}

// ---------------------------------------------------------------------------
// One GEMM+bias layer on the wave-private 32x256 LDS tile.
// Computes acc[8][4] (bias added) + LN mean/rstd per row.
// X layout: [32][260] (stride 260 floats). Wc: [32][256].
// ---------------------------------------------------------------------------
__device__ __forceinline__ void gemm_ln_stats(
    const float* __restrict__ W, const float* __restrict__ bias,
    float* X, float* Wc, int t,
    float acc[8][4], float mean[8], float rstd[8])
{
    const int lane = t & 63, w = t >> 6;
#pragma unroll
    for (int mi = 0; mi < 8; mi++)
#pragma unroll
        for (int c = 0; c < 4; c++) acc[mi][c] = 0.0f;

    for (int ch = 0; ch < 8; ch++) {
        __syncthreads();
#pragma unroll
        for (int i = 0; i < 8; i++) {
            const int q = i * 256 + t;
            const int kk = q >> 6, c4 = q & 63;
            *(float4*)&Wc[kk * 256 + c4 * 4] =
                *(const float4*)&W[(size_t)(ch * 32 + kk) * 256 + c4 * 4];
        }
        __syncthreads();
#pragma unroll
        for (int k4 = 0; k4 < 8; k4++) {
            float4 xq[8];
#pragma unroll
            for (int mi = 0; mi < 8; mi++)
                xq[mi] = *(const float4*)&X[(w * 8 + mi) * 260 + ch * 32 + k4 * 4];
#pragma unroll
            for (int j = 0; j < 4; j++) {
                const float4 wv = *(const float4*)&Wc[(k4 * 4 + j) * 256 + lane * 4];
#pragma unroll
                for (int mi = 0; mi < 8; mi++) {
                    const float xs = (j == 0) ? xq[mi].x : (j == 1) ? xq[mi].y
                                   : (j == 2) ? xq[mi].z : xq[mi].w;
                    acc[mi][0] += xs * wv.x;
                    acc[mi][1] += xs * wv.y;
                    acc[mi][2] += xs * wv.z;
                    acc[mi][3] += xs * wv.w;
                }
            }
        }
    }

    const int o = lane * 4;
    const float4 bv = *(const float4*)&bias[o];
#pragma unroll
    for (int mi = 0; mi < 8; mi++) {
        acc[mi][0] += bv.x; acc[mi][1] += bv.y; acc[mi][2] += bv.z; acc[mi][3] += bv.w;
        float s  = acc[mi][0] + acc[mi][1] + acc[mi][2] + acc[mi][3];
        float ss = acc[mi][0] * acc[mi][0] + acc[mi][1] * acc[mi][1] +
                   acc[mi][2] * acc[mi][2] + acc[mi][3] * acc[mi][3];
        s  = wave_sum(s);
        ss = wave_sum(ss);
        const float m = s * (1.0f / 256.0f);
        mean[mi] = m;
        rstd[mi] = rsqrtf(ss * (1.0f / 256.0f) - m * m + LN_EPS);
    }
}

// ---------------------------------------------------------------------------
// Fused loc MLP: 4x [GEMM+LN+SiLU] + final 256->1 projection. 1344 blocks.
// ---------------------------------------------------------------------------
__global__ __launch_bounds__(256) void loc_mlp(
    const float* __restrict__ Xin, const float* __restrict__ Ws,
    const float* __restrict__ bs, const float* __restrict__ lng,
    const float* __restrict__ lnb, const float* __restrict__ Wf,
    const float* __restrict__ bfp, float* __restrict__ logits)
{
    __shared__ float X[32 * 260];
    __shared__ float Wc[32 * 256];
    const int t = threadIdx.x, lane = t & 63, w = t >> 6;
    const int r0 = blockIdx.x * 32;

    // wave-private X load (wave w owns rows 8w..8w+7)
#pragma unroll
    for (int i = 0; i < 8; i++) {
        const int row = w * 8 + i;
        *(float4*)&X[row * 260 + lane * 4] =
            *(const float4*)&Xin[(size_t)(r0 + row) * 256 + lane * 4];
    }

    float acc[8][4], mean[8], rstd[8];
    for (int l = 0; l < 4; l++) {
        gemm_ln_stats(Ws + l * 65536, bs + l * 256, X, Wc, t, acc, mean, rstd);
        const int o = lane * 4;
        const float4 gv = *(const float4*)&lng[l * 256 + o];
        const float4 bb = *(const float4*)&lnb[l * 256 + o];
        const float gl[4] = {gv.x, gv.y, gv.z, gv.w};
        const float bl[4] = {bb.x, bb.y, bb.z, bb.w};
        if (l < 3) {
#pragma unroll
            for (int mi = 0; mi < 8; mi++) {
                float4 outv;
                float v0 = (acc[mi][0] - mean[mi]) * rstd[mi] * gl[0] + bl[0];
                float v1 = (acc[mi][1] - mean[mi]) * rstd[mi] * gl[1] + bl[1];
                float v2 = (acc[mi][2] - mean[mi]) * rstd[mi] * gl[2] + bl[2];
                float v3 = (acc[mi][3] - mean[mi]) * rstd[mi] * gl[3] + bl[3];
                outv.x = v0 * sigmoidf(v0); outv.y = v1 * sigmoidf(v1);
                outv.z = v2 * sigmoidf(v2); outv.w = v3 * sigmoidf(v3);
                *(float4*)&X[(w * 8 + mi) * 260 + o] = outv;   // in-place, wave-private
            }
        } else {
            const float4 wfv = *(const float4*)&Wf[o];
            const float wfl[4] = {wfv.x, wfv.y, wfv.z, wfv.w};
            const float bf0 = bfp[0];
#pragma unroll
            for (int mi = 0; mi < 8; mi++) {
                float p = 0.0f;
#pragma unroll
                for (int j = 0; j < 4; j++) {
                    float v = (acc[mi][j] - mean[mi]) * rstd[mi] * gl[j] + bl[j];
                    p += (v * sigmoidf(v)) * wfl[j];
                }
                p = wave_sum(p);
                if (lane == 0) logits[r0 + w * 8 + mi] = p + bf0;
            }
        }
    }
}

// ---------------------------------------------------------------------------
// Top-100 per batch (sorted desc, ties -> lower index). Grid B, block 256.
// ---------------------------------------------------------------------------
__global__ __launch_bounds__(256) void topk_kernel(
    const float* __restrict__ logits, int* __restrict__ idx_out,
    float* __restrict__ out, int B)
{
    __shared__ float v[5376];
    __shared__ float wv_s[4];
    __shared__ int wi_s[4];

    const int t = threadIdx.x, b = blockIdx.x;
    const int lane = t & 63, w = t >> 6;

    for (int i = t; i < 5376; i += 256) v[i] = logits[b * 5376 + i];
    __syncthreads();

    int cnt = 0;
    for (int k = 0; k < 100; k++) {
        float bv = -1e30f;
        int bi = 0x7fffffff;
        for (int i = t; i < 5376; i += 256) {
            const float val = v[i];
            if (val > bv) { bv = val; bi = i; }
        }
#pragma unroll
        for (int off = 32; off > 0; off >>= 1) {
            const float ov = __shfl_xor(bv, off, 64);
            const int oi = __shfl_xor(bi, off, 64);
            if (ov > bv || (ov == bv && oi < bi)) { bv = ov; bi = oi; }
        }
        if (lane == 0) { wv_s[w] = bv; wi_s[w] = bi; }
        __syncthreads();
        if (t == 0) {
            float fb = wv_s[0]; int fi = wi_s[0];
            for (int q = 1; q < 4; q++)
                if (wv_s[q] > fb || (wv_s[q] == fb && wi_s[q] < fi)) { fb = wv_s[q]; fi = wi_s[q]; }
            v[fi] = -1e30f;
            idx_out[b * 100 + k] = fi;
            out[B + b * 100 + k] = sigmoidf(fb);
            if (fb > 0.0f) cnt++;
        }
        __syncthreads();
    }
    if (t == 0) out[b] = (float)cnt;
}

// ---------------------------------------------------------------------------
// Fused heads: gather + 4 layers + final. Grid (25, 2): y==0 cls, y==1 box.
// ---------------------------------------------------------------------------
__global__ __launch_bounds__(256) void heads_mlp(
    const float* __restrict__ flat, const int* __restrict__ idxb,
    const float* __restrict__ cWs, const float* __restrict__ cbs,
    const float* __restrict__ cg, const float* __restrict__ cb,
    const float* __restrict__ cWf, const float* __restrict__ cbf,
    const float* __restrict__ xWs, const float* __restrict__ xbs,
    const float* __restrict__ xg, const float* __restrict__ xb_,
    const float* __restrict__ xWf, const float* __restrict__ xbf,
    const int* __restrict__ full_h, const int* __restrict__ full_w,
    float* __restrict__ out, int B)
{
    __shared__ float X[32 * 260];
    __shared__ float Wc[32 * 256];
    const int head = blockIdx.y;
    const float* Ws  = head ? xWs : cWs;
    const float* bsv = head ? xbs : cbs;
    const float* gv_ = head ? xg  : cg;
    const float* bv_ = head ? xb_ : cb;

    const int t = threadIdx.x, lane = t & 63, w = t >> 6;
    const int r0 = blockIdx.x * 32;

    // gather: wave-private rows
#pragma unroll
    for (int i = 0; i < 8; i++) {
        const int r = r0 + w * 8 + i;
        const int n = idxb[r];
        const int b = r / 100;
        *(float4*)&X[(w * 8 + i) * 260 + lane * 4] =
            *(const float4*)&flat[((size_t)b * 5376 + n) * 256 + lane * 4];
    }

    float acc[8][4], mean[8], rstd[8];
    for (int l = 0; l < 4; l++) {
        gemm_ln_stats(Ws + l * 65536, bsv + l * 256, X, Wc, t, acc, mean, rstd);
        const int o = lane * 4;
        const float4 gvv = *(const float4*)&gv_[l * 256 + o];
        const float4 bvv = *(const float4*)&bv_[l * 256 + o];
        const float gl[4] = {gvv.x, gvv.y, gvv.z, gvv.w};
        const float bl[4] = {bvv.x, bvv.y, bvv.z, bvv.w};
#pragma unroll
        for (int mi = 0; mi < 8; mi++) {
            float4 outv;
            float v0 = (acc[mi][0] - mean[mi]) * rstd[mi] * gl[0] + bl[0];
            float v1 = (acc[mi][1] - mean[mi]) * rstd[mi] * gl[1] + bl[1];
            float v2 = (acc[mi][2] - mean[mi]) * rstd[mi] * gl[2] + bl[2];
            float v3 = (acc[mi][3] - mean[mi]) * rstd[mi] * gl[3] + bl[3];
            outv.x = v0 * sigmoidf(v0); outv.y = v1 * sigmoidf(v1);
            outv.z = v2 * sigmoidf(v2); outv.w = v3 * sigmoidf(v3);
            *(float4*)&X[(w * 8 + mi) * 260 + o] = outv;
        }
    }
    __syncthreads();   // final stage uses a different thread->row mapping

    const int m = t >> 3, g = t & 7;
    if (head == 0) {
        // classes: argmax over 80 logits; lane-group g handles classes g*10..g*10+9
        const int jbase = g * 10;
        float lg[10];
#pragma unroll
        for (int jj = 0; jj < 10; jj++) lg[jj] = cbf[jbase + jj];
        for (int k = 0; k < 256; k++) {
            const float hv = X[m * 260 + k];
            const float* wr = &cWf[k * 80 + jbase];
#pragma unroll
            for (int jj = 0; jj < 10; jj++) lg[jj] += hv * wr[jj];
        }
        float best = lg[0]; int bj = jbase;
#pragma unroll
        for (int jj = 1; jj < 10; jj++)
            if (lg[jj] > best) { best = lg[jj]; bj = jbase + jj; }
#pragma unroll
        for (int off = 1; off < 8; off <<= 1) {
            const float ob = __shfl_xor(best, off, 64);
            const int oj = __shfl_xor(bj, off, 64);
            if (ob > best || (ob == best && oj < bj)) { best = ob; bj = oj; }
        }
        if (g == 0) out[B + B * 100 + r0 + m] = (float)bj;
    } else {
        // boxes
        float a[4] = {0.f, 0.f, 0.f, 0.f};
#pragma unroll
        for (int k4 = 0; k4 < 8; k4++) {
            const float4 hv = *(const float4*)&X[m * 260 + g * 32 + k4 * 4];
            const float h4[4] = {hv.x, hv.y, hv.z, hv.w};
#pragma unroll
            for (int j = 0; j < 4; j++) {
                const int k = g * 32 + k4 * 4 + j;
                const float4 wf = *(const float4*)&xWf[k * 4];
                a[0] += h4[j] * wf.x; a[1] += h4[j] * wf.y;
                a[2] += h4[j] * wf.z; a[3] += h4[j] * wf.w;
            }
        }
#pragma unroll
        for (int off = 1; off < 8; off <<= 1) {
            a[0] += __shfl_xor(a[0], off, 64);
            a[1] += __shfl_xor(a[1], off, 64);
            a[2] += __shfl_xor(a[2], off, 64);
            a[3] += __shfl_xor(a[3], off, 64);
        }
        if (g == 0) {
            const int r = r0 + m;
            const float e0 = a[0] + xbf[0], e1 = a[1] + xbf[1];
            const float e2 = a[2] + xbf[2], e3 = a[3] + xbf[3];
            const int n = idxb[r];
            int base, gw, gh;
            if (n < 4096)      { base = 0;    gw = 64; gh = 64; }
            else if (n < 5120) { base = 4096; gw = 32; gh = 32; }
            else               { base = 5120; gw = 16; gh = 16; }
            const int p = n - base;
            const int py = p / gw, px = p % gw;
            const float gx = (px + 0.5f) / gw;
            const float gy = (py + 0.5f) / gh;
            const float fw = (float)full_w[0], fh = (float)full_h[0];
            const int ob = B + 2 * B * 100;
            out[ob + r * 4 + 0] = (gx - 0.5f / gw * expf(e0)) * fw;
            out[ob + r * 4 + 1] = (gy - 0.5f / gh * expf(e1)) * fh;
            out[ob + r * 4 + 2] = (gx + 0.5f / gw * expf(e2)) * fw;
            out[ob + r * 4 + 3] = (gy + 0.5f / gh * expf(e3)) * fh;
        }
    }
}

extern "C" void kernel_launch(void* const* d_in, const int* in_sizes, int n_in,
                              void* d_out, int out_size, void* d_ws, size_t ws_size,
                              hipStream_t stream)
{
    const float* x3  = (const float*)d_in[0];
    const float* x4  = (const float*)d_in[1];
    const float* x5  = (const float*)d_in[2];
    const float* lw3 = (const float*)d_in[3];
    const float* lw4 = (const float*)d_in[4];
    const float* lw5 = (const float*)d_in[5];
    const float* bng = (const float*)d_in[6];
    const float* bnb = (const float*)d_in[7];
    const float* bnm = (const float*)d_in[8];
    const float* bnv = (const float*)d_in[9];

    const float* loc_Ws  = (const float*)d_in[10];
    const float* loc_bs  = (const float*)d_in[11];
    const float* loc_lng = (const float*)d_in[12];
    const float* loc_lnb = (const float*)d_in[13];
    const float* loc_Wf  = (const float*)d_in[14];
    const float* loc_bf  = (const float*)d_in[15];

    const float* cls_Ws  = (const float*)d_in[16];
    const float* cls_bs  = (const float*)d_in[17];
    const float* cls_lng = (const float*)d_in[18];
    const float* cls_lnb = (const float*)d_in[19];
    const float* cls_Wf  = (const float*)d_in[20];
    const float* cls_bf  = (const float*)d_in[21];

    const float* box_Ws  = (const float*)d_in[22];
    const float* box_bs  = (const float*)d_in[23];
    const float* box_lng = (const float*)d_in[24];
    const float* box_lnb = (const float*)d_in[25];
    const float* box_Wf  = (const float*)d_in[26];
    const float* box_bf  = (const float*)d_in[27];

    const int* full_h = (const int*)d_in[28];
    const int* full_w = (const int*)d_in[29];

    const int B = in_sizes[0] / (256 * 64 * 64);   // 8
    const int M = B * 5376;                        // 43008

    float* ws = (float*)d_ws;
    float* flat = ws;                                  // [M*256]
    float* loc  = flat + (size_t)M * 256;              // [M]
    int*   idxb = (int*)(loc + M);                     // [B*100] (padded to 1024)
    float* Wt3  = (float*)(idxb + 1024);               // [256*256]
    float* Wt4  = Wt3 + 256 * 256;                     // [512*256]
    float* Wt5  = Wt4 + 512 * 256;                     // [1024*256]

    float* out = (float*)d_out;
    const dim3 blk(256);

    // 0) transpose lateral weights to k-major
    transpose_w<<<dim3(256 / 32, 8), blk, 0, stream>>>(lw3, Wt3, 256);
    transpose_w<<<dim3(512 / 32, 8), blk, 0, stream>>>(lw4, Wt4, 512);
    transpose_w<<<dim3(1024 / 32, 8), blk, 0, stream>>>(lw5, Wt5, 1024);

    // 1) laterals -> flat    (blocks: 2048 / 1024 / 512)
    lateral_k<32, 128, 4, 8 ><<<dim3(128, B, 2), blk, 0, stream>>>(x3, Wt3, bng + 0,   bnb + 0,   bnm + 0,   bnv + 0,   flat, 4096, 0);
    lateral_k<32, 64,  2, 16><<<dim3(32,  B, 4), blk, 0, stream>>>(x4, Wt4, bng + 256, bnb + 256, bnm + 256, bnv + 256, flat, 1024, 4096);
    lateral_k<16, 64,  1, 32><<<dim3(16,  B, 4), blk, 0, stream>>>(x5, Wt5, bng + 512, bnb + 512, bnm + 512, bnv + 512, flat, 256,  5120);

    // 2) fused loc MLP -> logits
    loc_mlp<<<M / 32, blk, 0, stream>>>(flat, loc_Ws, loc_bs, loc_lng, loc_lnb, loc_Wf, loc_bf, loc);

    // 3) top-k
    topk_kernel<<<B, blk, 0, stream>>>(loc, idxb, out, B);

    // 4) both heads fused (gather + 4 layers + final)
    heads_mlp<<<dim3((B * 100) / 32, 2), blk, 0, stream>>>(
        flat, idxb,
        cls_Ws, cls_bs, cls_lng, cls_lnb, cls_Wf, cls_bf,
        box_Ws, box_bs, box_lng, box_lnb, box_Wf, box_bf,
        full_h, full_w, out, B);
}

// Round 3
// 943.997 us; speedup vs baseline: 1.7476x; 1.1793x over previous
//
#include <hip/hip_runtime.h>
#include <math.h>

#define LN_EPS 1e-5f

__device__ __forceinline__ float sigmoidf(float x) { return 1.0f / (1.0f + expf(-x)); }

__device__ __forceinline__ float wave_sum(float v) {
    v += __shfl_xor(v, 32, 64);
    v += __shfl_xor(v, 16, 64);
    v += __shfl_xor(v, 8, 64);
    v += __shfl_xor(v, 4, 64);
    v += __shfl_xor(v, 2, 64);
    v += __shfl_xor(v, 1, 64);
    return v;
}

// async global->LDS DMA, 16B per lane. lds ptr must be wave-uniform;
// lane i's slot = lds + i*16. gptr is the per-lane global address.
__device__ __forceinline__ void async_load16(const void* g, void* l) {
    __builtin_amdgcn_global_load_lds(
        (const __attribute__((address_space(1))) void*)g,
        (__attribute__((address_space(3))) void*)l, 16, 0, 0);
}

// ---------------------------------------------------------------------------
// W [256][Cin] -> Wt [Cin][256]. Grid (Cin/32, 256/32), block 256.
// ---------------------------------------------------------------------------
__global__ __launch_bounds__(256) void transpose_w(
    const float* __restrict__ W, float* __restrict__ Wt, int Cin)
{
    __shared__ float T[32][33];
    const int c0 = blockIdx.x * 32, o0 = blockIdx.y * 32;
    const int t = threadIdx.x;
    const int ci = t & 31, oi = t >> 5;
#pragma unroll
    for (int rep = 0; rep < 4; rep++)
        T[oi + rep * 8][ci] = W[(size_t)(o0 + oi + rep * 8) * Cin + c0 + ci];
    __syncthreads();
    const int oi2 = t & 31, ci2 = t >> 5;
#pragma unroll
    for (int rep = 0; rep < 4; rep++)
        Wt[(size_t)(c0 + ci2 + rep * 8) * 256 + o0 + oi2] = T[oi2][ci2 + rep * 8];
}

// ---------------------------------------------------------------------------
// Lateral 1x1 conv + BN + transpose to flat. Double-buffered async staging.
// Grid (HW/PX, B, 256/OT), block 256. Wt k-major [Cin][256].
// ---------------------------------------------------------------------------
template<int PX, int OT, int RPT, int CHUNKS>
__global__ __launch_bounds__(256) void lateral_k(
    const float* __restrict__ x,      // [B, Cin, HW]
    const float* __restrict__ Wt,     // [Cin, 256]
    const float* __restrict__ bng, const float* __restrict__ bnb,
    const float* __restrict__ bnm, const float* __restrict__ bnv,
    float* __restrict__ flat, int HW, int base)
{
    constexpr int GO = OT / 4;
    constexpr int WI = OT / 32;      // W DMA instrs per wave per chunk
    constexpr int XI = PX / 8;       // x DMA instrs per chunk (wave w < XI)
    __shared__ float Wc[2][32 * OT];
    __shared__ float sx[2][32 * PX];

    const int t = threadIdx.x, lane = t & 63, w = t >> 6;
    const int tc = t % GO;
    const int tr = t / GO;
    const int p0 = blockIdx.x * PX;
    const int b  = blockIdx.y;
    const int o0 = blockIdx.z * OT;
    const float* xb = x + (size_t)b * (CHUNKS * 32) * HW;

    float acc[RPT][4];
#pragma unroll
    for (int r = 0; r < RPT; r++)
#pragma unroll
        for (int c = 0; c < 4; c++) acc[r][c] = 0.0f;

    auto stage = [&](int ch, int buf) {
#pragma unroll
        for (int i = 0; i < WI; i++) {
            const int q = w * WI + i;              // wave-uniform
            const int f = q * 256 + lane * 4;      // flat float idx in [32][OT]
            const int kk = f / OT, col = f % OT;
            async_load16(&Wt[(size_t)(ch * 32 + kk) * 256 + o0 + col],
                         &Wc[buf][q * 256]);
        }
        if (w < XI) {
            const int f = w * 256 + lane * 4;      // flat float idx in [32][PX]
            const int kk = f / PX, col = f % PX;
            async_load16(&xb[(size_t)(ch * 32 + kk) * HW + p0 + col],
                         &sx[buf][w * 256]);
        }
    };

    stage(0, 0);
    for (int ch = 0; ch < CHUNKS; ch++) {
        __syncthreads();                            // drains chunk ch's DMA
        if (ch + 1 < CHUNKS) stage(ch + 1, (ch + 1) & 1);
        const float* Wb = Wc[ch & 1];
        const float* xv_ = sx[ch & 1];
#pragma unroll 8
        for (int kk = 0; kk < 32; kk++) {
            const float4 wv = *(const float4*)&Wb[kk * OT + tc * 4];
            float xv[RPT];
            if (RPT == 4) {
                const float4 xq = *(const float4*)&xv_[kk * PX + tr * 4];
                xv[0] = xq.x; xv[1] = xq.y; xv[2] = xq.z; xv[3] = xq.w;
            } else if (RPT == 2) {
                const float2 xq = *(const float2*)&xv_[kk * PX + tr * 2];
                xv[0] = xq.x; xv[1] = xq.y;
            } else {
                xv[0] = xv_[kk * PX + tr];
            }
#pragma unroll
            for (int r = 0; r < RPT; r++) {
                acc[r][0] += xv[r] * wv.x;
                acc[r][1] += xv[r] * wv.y;
                acc[r][2] += xv[r] * wv.z;
                acc[r][3] += xv[r] * wv.w;
            }
        }
    }

    const int o = o0 + tc * 4;
    const float4 gg = *(const float4*)&bng[o];
    const float4 bb = *(const float4*)&bnb[o];
    const float4 mm = *(const float4*)&bnm[o];
    const float4 vv = *(const float4*)&bnv[o];
    const float sc[4] = {gg.x * rsqrtf(vv.x + LN_EPS), gg.y * rsqrtf(vv.y + LN_EPS),
                         gg.z * rsqrtf(vv.z + LN_EPS), gg.w * rsqrtf(vv.w + LN_EPS)};
    const float mh[4] = {mm.x, mm.y, mm.z, mm.w};
    const float bh[4] = {bb.x, bb.y, bb.z, bb.w};

#pragma unroll
    for (int r = 0; r < RPT; r++) {
        const int p = p0 + tr * RPT + r;
        const size_t row = (size_t)b * 5376 + base + p;
        float4 outv;
        outv.x = (acc[r][0] - mh[0]) * sc[0] + bh[0];
        outv.y = (acc[r][1] - mh[1]) * sc[1] + bh[1];
        outv.z = (acc[r][2] - mh[2]) * sc[2] + bh[2];
        outv.w = (acc[r][3] - mh[3]) * sc[3] + bh[3];
        *(float4*)&flat[row * 256 + o] = outv;
    }
}

// ---------------------------------------------------------------------------
// One GEMM+bias+LN-stats layer on the wave-private 32x256 LDS tile.
// W staged in double-buffered 8-k chunks via async DMA. X stride 256 (no pad;
// X reads are wave-uniform broadcasts, conflict-free).
// ---------------------------------------------------------------------------
__device__ __forceinline__ void gemm8_pipelined(
    const float* __restrict__ Wg,    // [256][256] k-major
    const float* __restrict__ bias,
    float* X, float (*Wbuf)[8 * 256], int t,
    float acc[8][4], float mean[8], float rstd[8])
{
    const int lane = t & 63, w = t >> 6;
#pragma unroll
    for (int mi = 0; mi < 8; mi++)
#pragma unroll
        for (int c = 0; c < 4; c++) acc[mi][c] = 0.0f;

    // prologue: prefetch chunk 0 (2 rows of 1KB per wave)
#pragma unroll
    for (int i = 0; i < 2; i++) {
        const int q = w * 2 + i;
        async_load16(&Wg[(size_t)q * 256 + lane * 4], &Wbuf[0][q * 256]);
    }

    for (int ch = 0; ch < 32; ch++) {
        __syncthreads();                            // drains chunk ch's DMA
        if (ch + 1 < 32) {
#pragma unroll
            for (int i = 0; i < 2; i++) {
                const int q = w * 2 + i;
                async_load16(&Wg[(size_t)((ch + 1) * 8 + q) * 256 + lane * 4],
                             &Wbuf[(ch + 1) & 1][q * 256]);
            }
        }
        const float* Wb = Wbuf[ch & 1];
#pragma unroll
        for (int k4 = 0; k4 < 2; k4++) {
            float4 xq[8];
#pragma unroll
            for (int mi = 0; mi < 8; mi++)
                xq[mi] = *(const float4*)&X[(w * 8 + mi) * 256 + ch * 8 + k4 * 4];
#pragma unroll
            for (int j = 0; j < 4; j++) {
                const float4 wv = *(const float4*)&Wb[(k4 * 4 + j) * 256 + lane * 4];
#pragma unroll
                for (int mi = 0; mi < 8; mi++) {
                    const float xs = (j == 0) ? xq[mi].x : (j == 1) ? xq[mi].y
                                   : (j == 2) ? xq[mi].z : xq[mi].w;
                    acc[mi][0] += xs * wv.x;
                    acc[mi][1] += xs * wv.y;
                    acc[mi][2] += xs * wv.z;
                    acc[mi][3] += xs * wv.w;
                }
            }
        }
    }

    const int o = lane * 4;
    const float4 bv = *(const float4*)&bias[o];
#pragma unroll
    for (int mi = 0; mi < 8; mi++) {
        acc[mi][0] += bv.x; acc[mi][1] += bv.y; acc[mi][2] += bv.z; acc[mi][3] += bv.w;
        float s  = acc[mi][0] + acc[mi][1] + acc[mi][2] + acc[mi][3];
        float ss = acc[mi][0] * acc[mi][0] + acc[mi][1] * acc[mi][1] +
                   acc[mi][2] * acc[mi][2] + acc[mi][3] * acc[mi][3];
        s  = wave_sum(s);
        ss = wave_sum(ss);
        const float m = s * (1.0f / 256.0f);
        mean[mi] = m;
        rstd[mi] = rsqrtf(ss * (1.0f / 256.0f) - m * m + LN_EPS);
    }
}

// ---------------------------------------------------------------------------
// Fused loc MLP: 4x [GEMM+LN+SiLU] + final 256->1 projection. 1344 blocks.
// LDS: X 32KB + Wbuf 16KB = 48KB -> 3 blocks/CU.
// ---------------------------------------------------------------------------
__global__ __launch_bounds__(256) void loc_mlp(
    const float* __restrict__ Xin, const float* __restrict__ Ws,
    const float* __restrict__ bs, const float* __restrict__ lng,
    const float* __restrict__ lnb, const float* __restrict__ Wf,
    const float* __restrict__ bfp, float* __restrict__ logits)
{
    __shared__ float X[32 * 256];
    __shared__ float Wbuf[2][8 * 256];
    const int t = threadIdx.x, lane = t & 63, w = t >> 6;
    const int r0 = blockIdx.x * 32;

#pragma unroll
    for (int i = 0; i < 8; i++) {
        const int row = w * 8 + i;
        *(float4*)&X[row * 256 + lane * 4] =
            *(const float4*)&Xin[(size_t)(r0 + row) * 256 + lane * 4];
    }

    float acc[8][4], mean[8], rstd[8];
    for (int l = 0; l < 4; l++) {
        gemm8_pipelined(Ws + l * 65536, bs + l * 256, X, Wbuf, t, acc, mean, rstd);
        const int o = lane * 4;
        const float4 gv = *(const float4*)&lng[l * 256 + o];
        const float4 bb = *(const float4*)&lnb[l * 256 + o];
        const float gl[4] = {gv.x, gv.y, gv.z, gv.w};
        const float bl[4] = {bb.x, bb.y, bb.z, bb.w};
        if (l < 3) {
#pragma unroll
            for (int mi = 0; mi < 8; mi++) {
                float4 outv;
                float v0 = (acc[mi][0] - mean[mi]) * rstd[mi] * gl[0] + bl[0];
                float v1 = (acc[mi][1] - mean[mi]) * rstd[mi] * gl[1] + bl[1];
                float v2 = (acc[mi][2] - mean[mi]) * rstd[mi] * gl[2] + bl[2];
                float v3 = (acc[mi][3] - mean[mi]) * rstd[mi] * gl[3] + bl[3];
                outv.x = v0 * sigmoidf(v0); outv.y = v1 * sigmoidf(v1);
                outv.z = v2 * sigmoidf(v2); outv.w = v3 * sigmoidf(v3);
                *(float4*)&X[(w * 8 + mi) * 256 + o] = outv;   // wave-private
            }
        } else {
            const float4 wfv = *(const float4*)&Wf[o];
            const float wfl[4] = {wfv.x, wfv.y, wfv.z, wfv.w};
            const float bf0 = bfp[0];
#pragma unroll
            for (int mi = 0; mi < 8; mi++) {
                float p = 0.0f;
#pragma unroll
                for (int j = 0; j < 4; j++) {
                    float v = (acc[mi][j] - mean[mi]) * rstd[mi] * gl[j] + bl[j];
                    p += (v * sigmoidf(v)) * wfl[j];
                }
                p = wave_sum(p);
                if (lane == 0) logits[r0 + w * 8 + mi] = p + bf0;
            }
        }
    }
}

// ---------------------------------------------------------------------------
// Top-100 per batch (sorted desc, ties -> lower index). Grid B, block 256.
// ---------------------------------------------------------------------------
__global__ __launch_bounds__(256) void topk_kernel(
    const float* __restrict__ logits, int* __restrict__ idx_out,
    float* __restrict__ out, int B)
{
    __shared__ float v[5376];
    __shared__ float wv_s[4];
    __shared__ int wi_s[4];

    const int t = threadIdx.x, b = blockIdx.x;
    const int lane = t & 63, w = t >> 6;

    for (int i = t; i < 5376; i += 256) v[i] = logits[b * 5376 + i];
    __syncthreads();

    int cnt = 0;
    for (int k = 0; k < 100; k++) {
        float bv = -1e30f;
        int bi = 0x7fffffff;
        for (int i = t; i < 5376; i += 256) {
            const float val = v[i];
            if (val > bv) { bv = val; bi = i; }
        }
#pragma unroll
        for (int off = 32; off > 0; off >>= 1) {
            const float ov = __shfl_xor(bv, off, 64);
            const int oi = __shfl_xor(bi, off, 64);
            if (ov > bv || (ov == bv && oi < bi)) { bv = ov; bi = oi; }
        }
        if (lane == 0) { wv_s[w] = bv; wi_s[w] = bi; }
        __syncthreads();
        if (t == 0) {
            float fb = wv_s[0]; int fi = wi_s[0];
            for (int q = 1; q < 4; q++)
                if (wv_s[q] > fb || (wv_s[q] == fb && wi_s[q] < fi)) { fb = wv_s[q]; fi = wi_s[q]; }
            v[fi] = -1e30f;
            idx_out[b * 100 + k] = fi;
            out[B + b * 100 + k] = sigmoidf(fb);
            if (fb > 0.0f) cnt++;
        }
        __syncthreads();
    }
    if (t == 0) out[b] = (float)cnt;
}

// ---------------------------------------------------------------------------
// Fused heads: gather + 4 layers + final. Grid (25, 2): y==0 cls, y==1 box.
// ---------------------------------------------------------------------------
__global__ __launch_bounds__(256) void heads_mlp(
    const float* __restrict__ flat, const int* __restrict__ idxb,
    const float* __restrict__ cWs, const float* __restrict__ cbs,
    const float* __restrict__ cg, const float* __restrict__ cb,
    const float* __restrict__ cWf, const float* __restrict__ cbf,
    const float* __restrict__ xWs, const float* __restrict__ xbs,
    const float* __restrict__ xg, const float* __restrict__ xb_,
    const float* __restrict__ xWf, const float* __restrict__ xbf,
    const int* __restrict__ full_h, const int* __restrict__ full_w,
    float* __restrict__ out, int B)
{
    __shared__ float X[32 * 256];
    __shared__ float Wbuf[2][8 * 256];
    const int head = blockIdx.y;
    const float* Ws  = head ? xWs : cWs;
    const float* bsv = head ? xbs : cbs;
    const float* gv_ = head ? xg  : cg;
    const float* bv_ = head ? xb_ : cb;

    const int t = threadIdx.x, lane = t & 63, w = t >> 6;
    const int r0 = blockIdx.x * 32;

#pragma unroll
    for (int i = 0; i < 8; i++) {
        const int r = r0 + w * 8 + i;
        const int n = idxb[r];
        const int b = r / 100;
        *(float4*)&X[(w * 8 + i) * 256 + lane * 4] =
            *(const float4*)&flat[((size_t)b * 5376 + n) * 256 + lane * 4];
    }

    float acc[8][4], mean[8], rstd[8];
    for (int l = 0; l < 4; l++) {
        gemm8_pipelined(Ws + l * 65536, bsv + l * 256, X, Wbuf, t, acc, mean, rstd);
        const int o = lane * 4;
        const float4 gvv = *(const float4*)&gv_[l * 256 + o];
        const float4 bvv = *(const float4*)&bv_[l * 256 + o];
        const float gl[4] = {gvv.x, gvv.y, gvv.z, gvv.w};
        const float bl[4] = {bvv.x, bvv.y, bvv.z, bvv.w};
#pragma unroll
        for (int mi = 0; mi < 8; mi++) {
            float4 outv;
            float v0 = (acc[mi][0] - mean[mi]) * rstd[mi] * gl[0] + bl[0];
            float v1 = (acc[mi][1] - mean[mi]) * rstd[mi] * gl[1] + bl[1];
            float v2 = (acc[mi][2] - mean[mi]) * rstd[mi] * gl[2] + bl[2];
            float v3 = (acc[mi][3] - mean[mi]) * rstd[mi] * gl[3] + bl[3];
            outv.x = v0 * sigmoidf(v0); outv.y = v1 * sigmoidf(v1);
            outv.z = v2 * sigmoidf(v2); outv.w = v3 * sigmoidf(v3);
            *(float4*)&X[(w * 8 + mi) * 256 + o] = outv;
        }
    }
    __syncthreads();   // final stage uses a cross-wave thread->row mapping

    const int m = t >> 3, g = t & 7;
    if (head == 0) {
        const int jbase = g * 10;
        float lg[10];
#pragma unroll
        for (int jj = 0; jj < 10; jj++) lg[jj] = cbf[jbase + jj];
        for (int k = 0; k < 256; k++) {
            const float hv = X[m * 256 + k];
            const float* wr = &cWf[k * 80 + jbase];
#pragma unroll
            for (int jj = 0; jj < 10; jj++) lg[jj] += hv * wr[jj];
        }
        float best = lg[0]; int bj = jbase;
#pragma unroll
        for (int jj = 1; jj < 10; jj++)
            if (lg[jj] > best) { best = lg[jj]; bj = jbase + jj; }
#pragma unroll
        for (int off = 1; off < 8; off <<= 1) {
            const float ob = __shfl_xor(best, off, 64);
            const int oj = __shfl_xor(bj, off, 64);
            if (ob > best || (ob == best && oj < bj)) { best = ob; bj = oj; }
        }
        if (g == 0) out[B + B * 100 + r0 + m] = (float)bj;
    } else {
        float a[4] = {0.f, 0.f, 0.f, 0.f};
#pragma unroll
        for (int k4 = 0; k4 < 8; k4++) {
            const float4 hv = *(const float4*)&X[m * 256 + g * 32 + k4 * 4];
            const float h4[4] = {hv.x, hv.y, hv.z, hv.w};
#pragma unroll
            for (int j = 0; j < 4; j++) {
                const int k = g * 32 + k4 * 4 + j;
                const float4 wf = *(const float4*)&xWf[k * 4];
                a[0] += h4[j] * wf.x; a[1] += h4[j] * wf.y;
                a[2] += h4[j] * wf.z; a[3] += h4[j] * wf.w;
            }
        }
#pragma unroll
        for (int off = 1; off < 8; off <<= 1) {
            a[0] += __shfl_xor(a[0], off, 64);
            a[1] += __shfl_xor(a[1], off, 64);
            a[2] += __shfl_xor(a[2], off, 64);
            a[3] += __shfl_xor(a[3], off, 64);
        }
        if (g == 0) {
            const int r = r0 + m;
            const float e0 = a[0] + xbf[0], e1 = a[1] + xbf[1];
            const float e2 = a[2] + xbf[2], e3 = a[3] + xbf[3];
            const int n = idxb[r];
            int base, gw, gh;
            if (n < 4096)      { base = 0;    gw = 64; gh = 64; }
            else if (n < 5120) { base = 4096; gw = 32; gh = 32; }
            else               { base = 5120; gw = 16; gh = 16; }
            const int p = n - base;
            const int py = p / gw, px = p % gw;
            const float gx = (px + 0.5f) / gw;
            const float gy = (py + 0.5f) / gh;
            const float fw = (float)full_w[0], fh = (float)full_h[0];
            const int ob = B + 2 * B * 100;
            out[ob + r * 4 + 0] = (gx - 0.5f / gw * expf(e0)) * fw;
            out[ob + r * 4 + 1] = (gy - 0.5f / gh * expf(e1)) * fh;
            out[ob + r * 4 + 2] = (gx + 0.5f / gw * expf(e2)) * fw;
            out[ob + r * 4 + 3] = (gy + 0.5f / gh * expf(e3)) * fh;
        }
    }
}

extern "C" void kernel_launch(void* const* d_in, const int* in_sizes, int n_in,
                              void* d_out, int out_size, void* d_ws, size_t ws_size,
                              hipStream_t stream)
{
    const float* x3  = (const float*)d_in[0];
    const float* x4  = (const float*)d_in[1];
    const float* x5  = (const float*)d_in[2];
    const float* lw3 = (const float*)d_in[3];
    const float* lw4 = (const float*)d_in[4];
    const float* lw5 = (const float*)d_in[5];
    const float* bng = (const float*)d_in[6];
    const float* bnb = (const float*)d_in[7];
    const float* bnm = (const float*)d_in[8];
    const float* bnv = (const float*)d_in[9];

    const float* loc_Ws  = (const float*)d_in[10];
    const float* loc_bs  = (const float*)d_in[11];
    const float* loc_lng = (const float*)d_in[12];
    const float* loc_lnb = (const float*)d_in[13];
    const float* loc_Wf  = (const float*)d_in[14];
    const float* loc_bf  = (const float*)d_in[15];

    const float* cls_Ws  = (const float*)d_in[16];
    const float* cls_bs  = (const float*)d_in[17];
    const float* cls_lng = (const float*)d_in[18];
    const float* cls_lnb = (const float*)d_in[19];
    const float* cls_Wf  = (const float*)d_in[20];
    const float* cls_bf  = (const float*)d_in[21];

    const float* box_Ws  = (const float*)d_in[22];
    const float* box_bs  = (const float*)d_in[23];
    const float* box_lng = (const float*)d_in[24];
    const float* box_lnb = (const float*)d_in[25];
    const float* box_Wf  = (const float*)d_in[26];
    const float* box_bf  = (const float*)d_in[27];

    const int* full_h = (const int*)d_in[28];
    const int* full_w = (const int*)d_in[29];

    const int B = in_sizes[0] / (256 * 64 * 64);   // 8
    const int M = B * 5376;                        // 43008

    float* ws = (float*)d_ws;
    float* flat = ws;                                  // [M*256]
    float* loc  = flat + (size_t)M * 256;              // [M]
    int*   idxb = (int*)(loc + M);                     // [B*100] (padded to 1024)
    float* Wt3  = (float*)(idxb + 1024);               // [256*256]
    float* Wt4  = Wt3 + 256 * 256;                     // [512*256]
    float* Wt5  = Wt4 + 512 * 256;                     // [1024*256]

    float* out = (float*)d_out;
    const dim3 blk(256);

    // 0) transpose lateral weights to k-major
    transpose_w<<<dim3(256 / 32, 8), blk, 0, stream>>>(lw3, Wt3, 256);
    transpose_w<<<dim3(512 / 32, 8), blk, 0, stream>>>(lw4, Wt4, 512);
    transpose_w<<<dim3(1024 / 32, 8), blk, 0, stream>>>(lw5, Wt5, 1024);

    // 1) laterals -> flat   (blocks: 2048 / 1024 / 512)
    lateral_k<32, 128, 4, 8 ><<<dim3(128, B, 2), blk, 0, stream>>>(x3, Wt3, bng + 0,   bnb + 0,   bnm + 0,   bnv + 0,   flat, 4096, 0);
    lateral_k<32, 64,  2, 16><<<dim3(32,  B, 4), blk, 0, stream>>>(x4, Wt4, bng + 256, bnb + 256, bnm + 256, bnv + 256, flat, 1024, 4096);
    lateral_k<16, 64,  1, 32><<<dim3(16,  B, 4), blk, 0, stream>>>(x5, Wt5, bng + 512, bnb + 512, bnm + 512, bnv + 512, flat, 256,  5120);

    // 2) fused loc MLP -> logits
    loc_mlp<<<M / 32, blk, 0, stream>>>(flat, loc_Ws, loc_bs, loc_lng, loc_lnb, loc_Wf, loc_bf, loc);

    // 3) top-k
    topk_kernel<<<B, blk, 0, stream>>>(loc, idxb, out, B);

    // 4) both heads fused (gather + 4 layers + final)
    heads_mlp<<<dim3((B * 100) / 32, 2), blk, 0, stream>>>(
        flat, idxb,
        cls_Ws, cls_bs, cls_lng, cls_lnb, cls_Wf, cls_bf,
        box_Ws, box_bs, box_lng, box_lnb, box_Wf, box_bf,
        full_h, full_w, out, B);
}

// Round 5
// 940.903 us; speedup vs baseline: 1.7534x; 1.0033x over previous
//
#include <hip/hip_runtime.h>
#include <math.h>

#define LN_EPS 1e-5f

typedef __attribute__((ext_vector_type(8))) short bf16x8;
typedef __attribute__((ext_vector_type(4))) float f32x4;

__device__ __forceinline__ float sigmoidf(float x) { return 1.0f / (1.0f + expf(-x)); }

__device__ __forceinline__ unsigned short bf16_rn(float f) {
    unsigned u = __builtin_bit_cast(unsigned, f);
    return (unsigned short)((u + 0x7FFFu + ((u >> 16) & 1u)) >> 16);
}
__device__ __forceinline__ float bf16f(unsigned short h) {
    unsigned u = ((unsigned)h) << 16;
    return __builtin_bit_cast(float, u);
}

__device__ __forceinline__ float wave_sum(float v) {
    v += __shfl_xor(v, 32, 64);
    v += __shfl_xor(v, 16, 64);
    v += __shfl_xor(v, 8, 64);
    v += __shfl_xor(v, 4, 64);
    v += __shfl_xor(v, 2, 64);
    v += __shfl_xor(v, 1, 64);
    return v;
}

// async global->LDS DMA, 16B per lane (wave-uniform lds base, lane i -> +16i)
__device__ __forceinline__ void async_load16(const void* g, void* l) {
    __builtin_amdgcn_global_load_lds(
        (const __attribute__((address_space(1))) void*)g,
        (__attribute__((address_space(3))) void*)l, 16, 0, 0);
}

// ---------------------------------------------------------------------------
// W [256][Cin] -> Wt [Cin][256]. Grid (Cin/32, 256/32), block 256.
// ---------------------------------------------------------------------------
__global__ __launch_bounds__(256) void transpose_w(
    const float* __restrict__ W, float* __restrict__ Wt, int Cin)
{
    __shared__ float T[32][33];
    const int c0 = blockIdx.x * 32, o0 = blockIdx.y * 32;
    const int t = threadIdx.x;
    const int ci = t & 31, oi = t >> 5;
#pragma unroll
    for (int rep = 0; rep < 4; rep++)
        T[oi + rep * 8][ci] = W[(size_t)(o0 + oi + rep * 8) * Cin + c0 + ci];
    __syncthreads();
    const int oi2 = t & 31, ci2 = t >> 5;
#pragma unroll
    for (int rep = 0; rep < 4; rep++)
        Wt[(size_t)(c0 + ci2 + rep * 8) * 256 + o0 + oi2] = T[oi2][ci2 + rep * 8];
}

// ---------------------------------------------------------------------------
// Split [4][256][256] (k-major) weights into h/m/l bf16 planes in MFMA-B
// fragment order: frag g=(l*8+ks)*16+nt; lane holds
// B[k=ks*32+(lane>>4)*8+j][n=nt*16+(lane&15)], j=0..7 (16B/lane).
// Grid 128 x 256.
// ---------------------------------------------------------------------------
__global__ __launch_bounds__(256) void prep_wfrag3(
    const float* __restrict__ W,
    unsigned short* __restrict__ Wh, unsigned short* __restrict__ Wm,
    unsigned short* __restrict__ Wl)
{
    const int t = threadIdx.x;
    const int g = blockIdx.x * 4 + (t >> 6);
    const int lane = t & 63;
    const int nt = g & 15, ks = (g >> 4) & 7, l = g >> 7;
    const int n = nt * 16 + (lane & 15);
    const int k0 = ks * 32 + (lane >> 4) * 8;
    unsigned short h[8], m[8], lo[8];
#pragma unroll
    for (int j = 0; j < 8; j++) {
        const float f = W[(size_t)l * 65536 + (size_t)(k0 + j) * 256 + n];
        h[j] = bf16_rn(f);
        const float r1 = f - bf16f(h[j]);
        m[j] = bf16_rn(r1);
        lo[j] = bf16_rn(r1 - bf16f(m[j]));
    }
    const size_t o = ((size_t)g * 64 + lane) * 8;
#pragma unroll
    for (int j = 0; j < 8; j++) { Wh[o + j] = h[j]; Wm[o + j] = m[j]; Wl[o + j] = lo[j]; }
}

// ---------------------------------------------------------------------------
// Lateral 1x1 conv + BN + transpose to flat (fp32 VALU, double-buffered DMA).
// ---------------------------------------------------------------------------
template<int PX, int OT, int RPT, int CHUNKS>
__global__ __launch_bounds__(256) void lateral_k(
    const float* __restrict__ x, const float* __restrict__ Wt,
    const float* __restrict__ bng, const float* __restrict__ bnb,
    const float* __restrict__ bnm, const float* __restrict__ bnv,
    float* __restrict__ flat, int HW, int base)
{
    constexpr int GO = OT / 4;
    constexpr int WI = OT / 32;
    constexpr int XI = PX / 8;
    __shared__ float Wc[2][32 * OT];
    __shared__ float sx[2][32 * PX];

    const int t = threadIdx.x, lane = t & 63, w = t >> 6;
    const int tc = t % GO;
    const int tr = t / GO;
    const int p0 = blockIdx.x * PX;
    const int b  = blockIdx.y;
    const int o0 = blockIdx.z * OT;
    const float* xb = x + (size_t)b * (CHUNKS * 32) * HW;

    float acc[RPT][4];
#pragma unroll
    for (int r = 0; r < RPT; r++)
#pragma unroll
        for (int c = 0; c < 4; c++) acc[r][c] = 0.0f;

    auto stage = [&](int ch, int buf) {
#pragma unroll
        for (int i = 0; i < WI; i++) {
            const int q = w * WI + i;
            const int f = q * 256 + lane * 4;
            const int kk = f / OT, col = f % OT;
            async_load16(&Wt[(size_t)(ch * 32 + kk) * 256 + o0 + col],
                         &Wc[buf][q * 256]);
        }
        if (w < XI) {
            const int f = w * 256 + lane * 4;
            const int kk = f / PX, col = f % PX;
            async_load16(&xb[(size_t)(ch * 32 + kk) * HW + p0 + col],
                         &sx[buf][w * 256]);
        }
    };

    stage(0, 0);
    for (int ch = 0; ch < CHUNKS; ch++) {
        __syncthreads();
        if (ch + 1 < CHUNKS) stage(ch + 1, (ch + 1) & 1);
        const float* Wb = Wc[ch & 1];
        const float* xv_ = sx[ch & 1];
#pragma unroll 8
        for (int kk = 0; kk < 32; kk++) {
            const float4 wv = *(const float4*)&Wb[kk * OT + tc * 4];
            float xv[RPT];
            if (RPT == 4) {
                const float4 xq = *(const float4*)&xv_[kk * PX + tr * 4];
                xv[0] = xq.x; xv[1] = xq.y; xv[2] = xq.z; xv[3] = xq.w;
            } else if (RPT == 2) {
                const float2 xq = *(const float2*)&xv_[kk * PX + tr * 2];
                xv[0] = xq.x; xv[1] = xq.y;
            } else {
                xv[0] = xv_[kk * PX + tr];
            }
#pragma unroll
            for (int r = 0; r < RPT; r++) {
                acc[r][0] += xv[r] * wv.x;
                acc[r][1] += xv[r] * wv.y;
                acc[r][2] += xv[r] * wv.z;
                acc[r][3] += xv[r] * wv.w;
            }
        }
    }

    const int o = o0 + tc * 4;
    const float4 gg = *(const float4*)&bng[o];
    const float4 bb = *(const float4*)&bnb[o];
    const float4 mm = *(const float4*)&bnm[o];
    const float4 vv = *(const float4*)&bnv[o];
    const float sc[4] = {gg.x * rsqrtf(vv.x + LN_EPS), gg.y * rsqrtf(vv.y + LN_EPS),
                         gg.z * rsqrtf(vv.z + LN_EPS), gg.w * rsqrtf(vv.w + LN_EPS)};
    const float mh[4] = {mm.x, mm.y, mm.z, mm.w};
    const float bh[4] = {bb.x, bb.y, bb.z, bb.w};

#pragma unroll
    for (int r = 0; r < RPT; r++) {
        const int p = p0 + tr * RPT + r;
        const size_t row = (size_t)b * 5376 + base + p;
        float4 outv;
        outv.x = (acc[r][0] - mh[0]) * sc[0] + bh[0];
        outv.y = (acc[r][1] - mh[1]) * sc[1] + bh[1];
        outv.z = (acc[r][2] - mh[2]) * sc[2] + bh[2];
        outv.w = (acc[r][3] - mh[3]) * sc[3] + bh[3];
        *(float4*)&flat[row * 256 + o] = outv;
    }
}

// ---------------------------------------------------------------------------
// bf16x3 MFMA layer core: 6 products (hh, hm, mh, mm, hl, lh).
// acc[2][4] covers rows {mt*16+quad*4+r}, cols {w*64+nt*16+(lane&15)}.
// ---------------------------------------------------------------------------
__device__ __forceinline__ void mfma_layer3(
    const unsigned short* __restrict__ Wh, const unsigned short* __restrict__ Wm,
    const unsigned short* __restrict__ Wl,
    int l, int w, int lane,
    const unsigned short* Xh, const unsigned short* Xm, const unsigned short* Xl,
    f32x4 acc[2][4])
{
    const bf16x8* BH = (const bf16x8*)Wh;
    const bf16x8* BM = (const bf16x8*)Wm;
    const bf16x8* BL = (const bf16x8*)Wl;
#pragma unroll
    for (int mt = 0; mt < 2; mt++)
#pragma unroll
        for (int nt = 0; nt < 4; nt++) acc[mt][nt] = (f32x4){0.f, 0.f, 0.f, 0.f};
#pragma unroll
    for (int ks = 0; ks < 8; ks++) {
        const int ar = lane & 15;
        const int ao = ks * 32 + (lane >> 4) * 8;
        const bf16x8 ah0 = *(const bf16x8*)&Xh[ar * 256 + ao];
        const bf16x8 ah1 = *(const bf16x8*)&Xh[(ar + 16) * 256 + ao];
        const bf16x8 am0 = *(const bf16x8*)&Xm[ar * 256 + ao];
        const bf16x8 am1 = *(const bf16x8*)&Xm[(ar + 16) * 256 + ao];
        const bf16x8 al0 = *(const bf16x8*)&Xl[ar * 256 + ao];
        const bf16x8 al1 = *(const bf16x8*)&Xl[(ar + 16) * 256 + ao];
#pragma unroll
        for (int nt = 0; nt < 4; nt++) {
            const int fidx = ((l * 8 + ks) * 16 + (w * 4 + nt)) * 64 + lane;
            const bf16x8 bh = BH[fidx];
            const bf16x8 bm = BM[fidx];
            const bf16x8 bl = BL[fidx];
            acc[0][nt] = __builtin_amdgcn_mfma_f32_16x16x32_bf16(ah0, bh, acc[0][nt], 0, 0, 0);
            acc[1][nt] = __builtin_amdgcn_mfma_f32_16x16x32_bf16(ah1, bh, acc[1][nt], 0, 0, 0);
            acc[0][nt] = __builtin_amdgcn_mfma_f32_16x16x32_bf16(ah0, bm, acc[0][nt], 0, 0, 0);
            acc[1][nt] = __builtin_amdgcn_mfma_f32_16x16x32_bf16(ah1, bm, acc[1][nt], 0, 0, 0);
            acc[0][nt] = __builtin_amdgcn_mfma_f32_16x16x32_bf16(am0, bh, acc[0][nt], 0, 0, 0);
            acc[1][nt] = __builtin_amdgcn_mfma_f32_16x16x32_bf16(am1, bh, acc[1][nt], 0, 0, 0);
            acc[0][nt] = __builtin_amdgcn_mfma_f32_16x16x32_bf16(am0, bm, acc[0][nt], 0, 0, 0);
            acc[1][nt] = __builtin_amdgcn_mfma_f32_16x16x32_bf16(am1, bm, acc[1][nt], 0, 0, 0);
            acc[0][nt] = __builtin_amdgcn_mfma_f32_16x16x32_bf16(ah0, bl, acc[0][nt], 0, 0, 0);
            acc[1][nt] = __builtin_amdgcn_mfma_f32_16x16x32_bf16(ah1, bl, acc[1][nt], 0, 0, 0);
            acc[0][nt] = __builtin_amdgcn_mfma_f32_16x16x32_bf16(al0, bh, acc[0][nt], 0, 0, 0);
            acc[1][nt] = __builtin_amdgcn_mfma_f32_16x16x32_bf16(al1, bh, acc[1][nt], 0, 0, 0);
        }
    }
}

// bias add + cross-wave LN stats (one internal __syncthreads).
__device__ __forceinline__ void ln_stats(
    f32x4 acc[2][4], const float* __restrict__ bias,
    int w, int lane, float* red, float mean[2][4], float rstd[2][4])
{
    const int colb = lane & 15;
    float bvs[4];
#pragma unroll
    for (int nt = 0; nt < 4; nt++) bvs[nt] = bias[w * 64 + nt * 16 + colb];
#pragma unroll
    for (int mt = 0; mt < 2; mt++)
#pragma unroll
        for (int nt = 0; nt < 4; nt++)
#pragma unroll
            for (int r = 0; r < 4; r++) acc[mt][nt][r] += bvs[nt];

#pragma unroll
    for (int mt = 0; mt < 2; mt++)
#pragma unroll
        for (int r = 0; r < 4; r++) {
            float s = acc[mt][0][r] + acc[mt][1][r] + acc[mt][2][r] + acc[mt][3][r];
            float ss = acc[mt][0][r] * acc[mt][0][r] + acc[mt][1][r] * acc[mt][1][r] +
                       acc[mt][2][r] * acc[mt][2][r] + acc[mt][3][r] * acc[mt][3][r];
#pragma unroll
            for (int off = 1; off < 16; off <<= 1) {
                s  += __shfl_xor(s, off, 64);
                ss += __shfl_xor(ss, off, 64);
            }
            if (colb == 0) {
                const int row = mt * 16 + (lane >> 4) * 4 + r;
                red[w * 64 + row] = s;
                red[256 + w * 64 + row] = ss;
            }
        }
    __syncthreads();
#pragma unroll
    for (int mt = 0; mt < 2; mt++)
#pragma unroll
        for (int r = 0; r < 4; r++) {
            const int row = mt * 16 + (lane >> 4) * 4 + r;
            const float s  = red[row] + red[64 + row] + red[128 + row] + red[192 + row];
            const float ss = red[256 + row] + red[320 + row] + red[384 + row] + red[448 + row];
            const float m = s * (1.0f / 256.0f);
            mean[mt][r] = m;
            rstd[mt][r] = rsqrtf(ss * (1.0f / 256.0f) - m * m + LN_EPS);
        }
}

// LN apply + SiLU + 3-way split back into X planes (wave-disjoint cols).
__device__ __forceinline__ void write_x3(
    f32x4 acc[2][4], const float mean[2][4], const float rstd[2][4],
    const float* __restrict__ g, const float* __restrict__ b,
    int w, int lane, unsigned short* Xh, unsigned short* Xm, unsigned short* Xl)
{
    const int colb = lane & 15;
#pragma unroll
    for (int nt = 0; nt < 4; nt++) {
        const int col = w * 64 + nt * 16 + colb;
        const float gc = g[col], bc = b[col];
#pragma unroll
        for (int mt = 0; mt < 2; mt++)
#pragma unroll
            for (int r = 0; r < 4; r++) {
                const int row = mt * 16 + (lane >> 4) * 4 + r;
                float v = (acc[mt][nt][r] - mean[mt][r]) * rstd[mt][r] * gc + bc;
                v = v * sigmoidf(v);
                const unsigned short h = bf16_rn(v);
                const float r1 = v - bf16f(h);
                const unsigned short m = bf16_rn(r1);
                Xh[row * 256 + col] = h;
                Xm[row * 256 + col] = m;
                Xl[row * 256 + col] = bf16_rn(r1 - bf16f(m));
            }
    }
}

// ---------------------------------------------------------------------------
// Fused loc MLP (bf16x3 MFMA): 4 layers + fused 256->1 projection. Grid M/32.
// LDS: 3*16KB X planes + red 2KB = 50KB -> 3 blocks/CU.
// ---------------------------------------------------------------------------
__global__ __launch_bounds__(256, 3) void loc_mlp_mfma3(
    const float* __restrict__ Xin,
    const unsigned short* __restrict__ Wh, const unsigned short* __restrict__ Wm,
    const unsigned short* __restrict__ Wl,
    const float* __restrict__ bs, const float* __restrict__ lng,
    const float* __restrict__ lnb, const float* __restrict__ Wf,
    const float* __restrict__ bfp, float* __restrict__ logits)
{
    __shared__ unsigned short Xh[32 * 256];
    __shared__ unsigned short Xm[32 * 256];
    __shared__ unsigned short Xl[32 * 256];
    __shared__ float red[512];
    const int t = threadIdx.x, lane = t & 63, w = t >> 6;
    const int r0 = blockIdx.x * 32;

    const float* Xg = Xin + (size_t)r0 * 256;
#pragma unroll
    for (int i = 0; i < 8; i++) {
        const int f = i * 1024 + t * 4;
        const int row = f >> 8, col = f & 255;
        const float4 v = *(const float4*)&Xg[f];
        ushort4 h, m, lo;
        h.x = bf16_rn(v.x); { float r1 = v.x - bf16f(h.x); m.x = bf16_rn(r1); lo.x = bf16_rn(r1 - bf16f(m.x)); }
        h.y = bf16_rn(v.y); { float r1 = v.y - bf16f(h.y); m.y = bf16_rn(r1); lo.y = bf16_rn(r1 - bf16f(m.y)); }
        h.z = bf16_rn(v.z); { float r1 = v.z - bf16f(h.z); m.z = bf16_rn(r1); lo.z = bf16_rn(r1 - bf16f(m.z)); }
        h.w = bf16_rn(v.w); { float r1 = v.w - bf16f(h.w); m.w = bf16_rn(r1); lo.w = bf16_rn(r1 - bf16f(m.w)); }
        *(ushort4*)&Xh[row * 256 + col] = h;
        *(ushort4*)&Xm[row * 256 + col] = m;
        *(ushort4*)&Xl[row * 256 + col] = lo;
    }

    f32x4 acc[2][4];
    float mean[2][4], rstd[2][4];
    for (int l = 0; l < 4; l++) {
        __syncthreads();                      // X ready
        mfma_layer3(Wh, Wm, Wl, l, w, lane, Xh, Xm, Xl, acc);
        ln_stats(acc, bs + l * 256, w, lane, red, mean, rstd);
        if (l < 3) {
            write_x3(acc, mean, rstd, lng + l * 256, lnb + l * 256, w, lane, Xh, Xm, Xl);
        } else {
            const int colb = lane & 15;
            float p[2][4];
#pragma unroll
            for (int mt = 0; mt < 2; mt++)
#pragma unroll
                for (int r = 0; r < 4; r++) p[mt][r] = 0.0f;
#pragma unroll
            for (int nt = 0; nt < 4; nt++) {
                const int col = w * 64 + nt * 16 + colb;
                const float gc = lng[3 * 256 + col], bc = lnb[3 * 256 + col];
                const float wf = Wf[col];
#pragma unroll
                for (int mt = 0; mt < 2; mt++)
#pragma unroll
                    for (int r = 0; r < 4; r++) {
                        float v = (acc[mt][nt][r] - mean[mt][r]) * rstd[mt][r] * gc + bc;
                        p[mt][r] += (v * sigmoidf(v)) * wf;
                    }
            }
            __syncthreads();
#pragma unroll
            for (int mt = 0; mt < 2; mt++)
#pragma unroll
                for (int r = 0; r < 4; r++) {
                    float s = p[mt][r];
#pragma unroll
                    for (int off = 1; off < 16; off <<= 1) s += __shfl_xor(s, off, 64);
                    if (colb == 0)
                        red[w * 64 + mt * 16 + (lane >> 4) * 4 + r] = s;
                }
            __syncthreads();
            if (t < 32)
                logits[r0 + t] = red[t] + red[64 + t] + red[128 + t] + red[192 + t] + bfp[0];
        }
    }
}

// ---------------------------------------------------------------------------
// Top-100 per batch (sorted desc, ties -> lower index). Grid B, block 256.
// ---------------------------------------------------------------------------
__global__ __launch_bounds__(256) void topk_kernel(
    const float* __restrict__ logits, int* __restrict__ idx_out,
    float* __restrict__ out, int B)
{
    __shared__ float v[5376];
    __shared__ float wv_s[4];
    __shared__ int wi_s[4];

    const int t = threadIdx.x, b = blockIdx.x;
    const int lane = t & 63, w = t >> 6;

    for (int i = t; i < 5376; i += 256) v[i] = logits[b * 5376 + i];
    __syncthreads();

    int cnt = 0;
    for (int k = 0; k < 100; k++) {
        float bv = -1e30f;
        int bi = 0x7fffffff;
        for (int i = t; i < 5376; i += 256) {
            const float val = v[i];
            if (val > bv) { bv = val; bi = i; }
        }
#pragma unroll
        for (int off = 32; off > 0; off >>= 1) {
            const float ov = __shfl_xor(bv, off, 64);
            const int oi = __shfl_xor(bi, off, 64);
            if (ov > bv || (ov == bv && oi < bi)) { bv = ov; bi = oi; }
        }
        if (lane == 0) { wv_s[w] = bv; wi_s[w] = bi; }
        __syncthreads();
        if (t == 0) {
            float fb = wv_s[0]; int fi = wi_s[0];
            for (int q = 1; q < 4; q++)
                if (wv_s[q] > fb || (wv_s[q] == fb && wi_s[q] < fi)) { fb = wv_s[q]; fi = wi_s[q]; }
            v[fi] = -1e30f;
            idx_out[b * 100 + k] = fi;
            out[B + b * 100 + k] = sigmoidf(fb);
            if (fb > 0.0f) cnt++;
        }
        __syncthreads();
    }
    if (t == 0) out[b] = (float)cnt;
}

// ---------------------------------------------------------------------------
// fp32 GEMM+bias+LN-stats on the wave-private 32x256 LDS tile (R3 core).
// ---------------------------------------------------------------------------
__device__ __forceinline__ void gemm8_pipelined(
    const float* __restrict__ Wg, const float* __restrict__ bias,
    float* X, float (*Wbuf)[8 * 256], int t,
    float acc[8][4], float mean[8], float rstd[8])
{
    const int lane = t & 63, w = t >> 6;
#pragma unroll
    for (int mi = 0; mi < 8; mi++)
#pragma unroll
        for (int c = 0; c < 4; c++) acc[mi][c] = 0.0f;

#pragma unroll
    for (int i = 0; i < 2; i++) {
        const int q = w * 2 + i;
        async_load16(&Wg[(size_t)q * 256 + lane * 4], &Wbuf[0][q * 256]);
    }

    for (int ch = 0; ch < 32; ch++) {
        __syncthreads();
        if (ch + 1 < 32) {
#pragma unroll
            for (int i = 0; i < 2; i++) {
                const int q = w * 2 + i;
                async_load16(&Wg[(size_t)((ch + 1) * 8 + q) * 256 + lane * 4],
                             &Wbuf[(ch + 1) & 1][q * 256]);
            }
        }
        const float* Wb = Wbuf[ch & 1];
#pragma unroll
        for (int k4 = 0; k4 < 2; k4++) {
            float4 xq[8];
#pragma unroll
            for (int mi = 0; mi < 8; mi++)
                xq[mi] = *(const float4*)&X[(w * 8 + mi) * 256 + ch * 8 + k4 * 4];
#pragma unroll
            for (int j = 0; j < 4; j++) {
                const float4 wv = *(const float4*)&Wb[(k4 * 4 + j) * 256 + lane * 4];
#pragma unroll
                for (int mi = 0; mi < 8; mi++) {
                    const float xs = (j == 0) ? xq[mi].x : (j == 1) ? xq[mi].y
                                   : (j == 2) ? xq[mi].z : xq[mi].w;
                    acc[mi][0] += xs * wv.x;
                    acc[mi][1] += xs * wv.y;
                    acc[mi][2] += xs * wv.z;
                    acc[mi][3] += xs * wv.w;
                }
            }
        }
    }

    const int o = lane * 4;
    const float4 bv = *(const float4*)&bias[o];
#pragma unroll
    for (int mi = 0; mi < 8; mi++) {
        acc[mi][0] += bv.x; acc[mi][1] += bv.y; acc[mi][2] += bv.z; acc[mi][3] += bv.w;
        float s  = acc[mi][0] + acc[mi][1] + acc[mi][2] + acc[mi][3];
        float ss = acc[mi][0] * acc[mi][0] + acc[mi][1] * acc[mi][1] +
                   acc[mi][2] * acc[mi][2] + acc[mi][3] * acc[mi][3];
        s  = wave_sum(s);
        ss = wave_sum(ss);
        const float m = s * (1.0f / 256.0f);
        mean[mi] = m;
        rstd[mi] = rsqrtf(ss * (1.0f / 256.0f) - m * m + LN_EPS);
    }
}

// ---------------------------------------------------------------------------
// Fused heads (fp32, R3-proven): gather + 4 layers + finals. Grid (25,2).
// ---------------------------------------------------------------------------
__global__ __launch_bounds__(256) void heads_mlp(
    const float* __restrict__ flat, const int* __restrict__ idxb,
    const float* __restrict__ cWs, const float* __restrict__ cbs,
    const float* __restrict__ cg, const float* __restrict__ cb,
    const float* __restrict__ cWf, const float* __restrict__ cbf,
    const float* __restrict__ xWs, const float* __restrict__ xbs,
    const float* __restrict__ xg, const float* __restrict__ xb_,
    const float* __restrict__ xWf, const float* __restrict__ xbf,
    const int* __restrict__ full_h, const int* __restrict__ full_w,
    float* __restrict__ out, int B)
{
    __shared__ float X[32 * 256];
    __shared__ float Wbuf[2][8 * 256];
    const int head = blockIdx.y;
    const float* Ws  = head ? xWs : cWs;
    const float* bsv = head ? xbs : cbs;
    const float* gv_ = head ? xg  : cg;
    const float* bv_ = head ? xb_ : cb;

    const int t = threadIdx.x, lane = t & 63, w = t >> 6;
    const int r0 = blockIdx.x * 32;

#pragma unroll
    for (int i = 0; i < 8; i++) {
        const int r = r0 + w * 8 + i;
        const int n = idxb[r];
        const int b = r / 100;
        *(float4*)&X[(w * 8 + i) * 256 + lane * 4] =
            *(const float4*)&flat[((size_t)b * 5376 + n) * 256 + lane * 4];
    }

    float acc[8][4], mean[8], rstd[8];
    for (int l = 0; l < 4; l++) {
        gemm8_pipelined(Ws + l * 65536, bsv + l * 256, X, Wbuf, t, acc, mean, rstd);
        const int o = lane * 4;
        const float4 gvv = *(const float4*)&gv_[l * 256 + o];
        const float4 bvv = *(const float4*)&bv_[l * 256 + o];
        const float gl[4] = {gvv.x, gvv.y, gvv.z, gvv.w};
        const float bl[4] = {bvv.x, bvv.y, bvv.z, bvv.w};
#pragma unroll
        for (int mi = 0; mi < 8; mi++) {
            float4 outv;
            float v0 = (acc[mi][0] - mean[mi]) * rstd[mi] * gl[0] + bl[0];
            float v1 = (acc[mi][1] - mean[mi]) * rstd[mi] * gl[1] + bl[1];
            float v2 = (acc[mi][2] - mean[mi]) * rstd[mi] * gl[2] + bl[2];
            float v3 = (acc[mi][3] - mean[mi]) * rstd[mi] * gl[3] + bl[3];
            outv.x = v0 * sigmoidf(v0); outv.y = v1 * sigmoidf(v1);
            outv.z = v2 * sigmoidf(v2); outv.w = v3 * sigmoidf(v3);
            *(float4*)&X[(w * 8 + mi) * 256 + o] = outv;
        }
    }
    __syncthreads();

    const int m = t >> 3, g = t & 7;
    if (head == 0) {
        const int jbase = g * 10;
        float lg[10];
#pragma unroll
        for (int jj = 0; jj < 10; jj++) lg[jj] = cbf[jbase + jj];
        for (int k = 0; k < 256; k++) {
            const float hv = X[m * 256 + k];
            const float* wr = &cWf[k * 80 + jbase];
#pragma unroll
            for (int jj = 0; jj < 10; jj++) lg[jj] += hv * wr[jj];
        }
        float best = lg[0]; int bj = jbase;
#pragma unroll
        for (int jj = 1; jj < 10; jj++)
            if (lg[jj] > best) { best = lg[jj]; bj = jbase + jj; }
#pragma unroll
        for (int off = 1; off < 8; off <<= 1) {
            const float ob = __shfl_xor(best, off, 64);
            const int oj = __shfl_xor(bj, off, 64);
            if (ob > best || (ob == best && oj < bj)) { best = ob; bj = oj; }
        }
        if (g == 0) out[B + B * 100 + r0 + m] = (float)bj;
    } else {
        float a[4] = {0.f, 0.f, 0.f, 0.f};
#pragma unroll
        for (int k4 = 0; k4 < 8; k4++) {
            const float4 hv = *(const float4*)&X[m * 256 + g * 32 + k4 * 4];
            const float h4[4] = {hv.x, hv.y, hv.z, hv.w};
#pragma unroll
            for (int j = 0; j < 4; j++) {
                const int k = g * 32 + k4 * 4 + j;
                const float4 wf = *(const float4*)&xWf[k * 4];
                a[0] += h4[j] * wf.x; a[1] += h4[j] * wf.y;
                a[2] += h4[j] * wf.z; a[3] += h4[j] * wf.w;
            }
        }
#pragma unroll
        for (int off = 1; off < 8; off <<= 1) {
            a[0] += __shfl_xor(a[0], off, 64);
            a[1] += __shfl_xor(a[1], off, 64);
            a[2] += __shfl_xor(a[2], off, 64);
            a[3] += __shfl_xor(a[3], off, 64);
        }
        if (g == 0) {
            const int r = r0 + m;
            const float e0 = a[0] + xbf[0], e1 = a[1] + xbf[1];
            const float e2 = a[2] + xbf[2], e3 = a[3] + xbf[3];
            const int n = idxb[r];
            int base, gw, gh;
            if (n < 4096)      { base = 0;    gw = 64; gh = 64; }
            else if (n < 5120) { base = 4096; gw = 32; gh = 32; }
            else               { base = 5120; gw = 16; gh = 16; }
            const int p = n - base;
            const int py = p / gw, px = p % gw;
            const float gx = (px + 0.5f) / gw;
            const float gy = (py + 0.5f) / gh;
            const float fw = (float)full_w[0], fh = (float)full_h[0];
            const int ob = B + 2 * B * 100;
            out[ob + r * 4 + 0] = (gx - 0.5f / gw * expf(e0)) * fw;
            out[ob + r * 4 + 1] = (gy - 0.5f / gh * expf(e1)) * fh;
            out[ob + r * 4 + 2] = (gx + 0.5f / gw * expf(e2)) * fw;
            out[ob + r * 4 + 3] = (gy + 0.5f / gh * expf(e3)) * fh;
        }
    }
}

extern "C" void kernel_launch(void* const* d_in, const int* in_sizes, int n_in,
                              void* d_out, int out_size, void* d_ws, size_t ws_size,
                              hipStream_t stream)
{
    const float* x3  = (const float*)d_in[0];
    const float* x4  = (const float*)d_in[1];
    const float* x5  = (const float*)d_in[2];
    const float* lw3 = (const float*)d_in[3];
    const float* lw4 = (const float*)d_in[4];
    const float* lw5 = (const float*)d_in[5];
    const float* bng = (const float*)d_in[6];
    const float* bnb = (const float*)d_in[7];
    const float* bnm = (const float*)d_in[8];
    const float* bnv = (const float*)d_in[9];

    const float* loc_Ws  = (const float*)d_in[10];
    const float* loc_bs  = (const float*)d_in[11];
    const float* loc_lng = (const float*)d_in[12];
    const float* loc_lnb = (const float*)d_in[13];
    const float* loc_Wf  = (const float*)d_in[14];
    const float* loc_bf  = (const float*)d_in[15];

    const float* cls_Ws  = (const float*)d_in[16];
    const float* cls_bs  = (const float*)d_in[17];
    const float* cls_lng = (const float*)d_in[18];
    const float* cls_lnb = (const float*)d_in[19];
    const float* cls_Wf  = (const float*)d_in[20];
    const float* cls_bf  = (const float*)d_in[21];

    const float* box_Ws  = (const float*)d_in[22];
    const float* box_bs  = (const float*)d_in[23];
    const float* box_lng = (const float*)d_in[24];
    const float* box_lnb = (const float*)d_in[25];
    const float* box_Wf  = (const float*)d_in[26];
    const float* box_bf  = (const float*)d_in[27];

    const int* full_h = (const int*)d_in[28];
    const int* full_w = (const int*)d_in[29];

    const int B = in_sizes[0] / (256 * 64 * 64);   // 8
    const int M = B * 5376;                        // 43008

    float* ws = (float*)d_ws;
    float* flat = ws;                                  // [M*256]
    float* loc  = flat + (size_t)M * 256;              // [M]
    int*   idxb = (int*)(loc + M);                     // [B*100] (padded 1024)
    float* Wt3  = (float*)(idxb + 1024);               // [256*256]
    float* Wt4  = Wt3 + 256 * 256;                     // [512*256]
    float* Wt5  = Wt4 + 512 * 256;                     // [1024*256]
    unsigned short* locWh = (unsigned short*)(Wt5 + 1024 * 256);
    unsigned short* locWm = locWh + 262144;            // 4*8*16*64*8
    unsigned short* locWl = locWm + 262144;

    float* out = (float*)d_out;
    const dim3 blk(256);

    // 0) weight preprocessing
    transpose_w<<<dim3(256 / 32, 8), blk, 0, stream>>>(lw3, Wt3, 256);
    transpose_w<<<dim3(512 / 32, 8), blk, 0, stream>>>(lw4, Wt4, 512);
    transpose_w<<<dim3(1024 / 32, 8), blk, 0, stream>>>(lw5, Wt5, 1024);
    prep_wfrag3<<<128, blk, 0, stream>>>(loc_Ws, locWh, locWm, locWl);

    // 1) laterals -> flat
    lateral_k<32, 128, 4, 8 ><<<dim3(128, B, 2), blk, 0, stream>>>(x3, Wt3, bng + 0,   bnb + 0,   bnm + 0,   bnv + 0,   flat, 4096, 0);
    lateral_k<32, 64,  2, 16><<<dim3(32,  B, 4), blk, 0, stream>>>(x4, Wt4, bng + 256, bnb + 256, bnm + 256, bnv + 256, flat, 1024, 4096);
    lateral_k<16, 64,  1, 32><<<dim3(16,  B, 4), blk, 0, stream>>>(x5, Wt5, bng + 512, bnb + 512, bnm + 512, bnv + 512, flat, 256,  5120);

    // 2) fused loc MLP (bf16x3 MFMA) -> logits
    loc_mlp_mfma3<<<M / 32, blk, 0, stream>>>(flat, locWh, locWm, locWl, loc_bs,
                                              loc_lng, loc_lnb, loc_Wf, loc_bf, loc);

    // 3) top-k
    topk_kernel<<<B, blk, 0, stream>>>(loc, idxb, out, B);

    // 4) both heads (fp32, proven)
    heads_mlp<<<dim3((B * 100) / 32, 2), blk, 0, stream>>>(
        flat, idxb,
        cls_Ws, cls_bs, cls_lng, cls_lnb, cls_Wf, cls_bf,
        box_Ws, box_bs, box_lng, box_lnb, box_Wf, box_bf,
        full_h, full_w, out, B);
}

// Round 6
// 921.208 us; speedup vs baseline: 1.7908x; 1.0214x over previous
//
#include <hip/hip_runtime.h>
#include <math.h>

#define LN_EPS 1e-5f
#define XS 264   // padded X row stride in bf16 elems (132 dwords ≡ 4 mod 32 banks)

typedef __attribute__((ext_vector_type(8))) short bf16x8;
typedef __attribute__((ext_vector_type(4))) float f32x4;

__device__ __forceinline__ float sigmoidf(float x) { return 1.0f / (1.0f + expf(-x)); }

__device__ __forceinline__ unsigned short bf16_rn(float f) {
    unsigned u = __builtin_bit_cast(unsigned, f);
    return (unsigned short)((u + 0x7FFFu + ((u >> 16) & 1u)) >> 16);
}
__device__ __forceinline__ float bf16f(unsigned short h) {
    unsigned u = ((unsigned)h) << 16;
    return __builtin_bit_cast(float, u);
}

__device__ __forceinline__ float wave_sum(float v) {
    v += __shfl_xor(v, 32, 64);
    v += __shfl_xor(v, 16, 64);
    v += __shfl_xor(v, 8, 64);
    v += __shfl_xor(v, 4, 64);
    v += __shfl_xor(v, 2, 64);
    v += __shfl_xor(v, 1, 64);
    return v;
}

// async global->LDS DMA, 16B per lane (wave-uniform lds base, lane i -> +16i)
__device__ __forceinline__ void async_load16(const void* g, void* l) {
    __builtin_amdgcn_global_load_lds(
        (const __attribute__((address_space(1))) void*)g,
        (__attribute__((address_space(3))) void*)l, 16, 0, 0);
}

// ---------------------------------------------------------------------------
// W [256][Cin] -> Wt [Cin][256]. Grid (Cin/32, 256/32), block 256.
// ---------------------------------------------------------------------------
__global__ __launch_bounds__(256) void transpose_w(
    const float* __restrict__ W, float* __restrict__ Wt, int Cin)
{
    __shared__ float T[32][33];
    const int c0 = blockIdx.x * 32, o0 = blockIdx.y * 32;
    const int t = threadIdx.x;
    const int ci = t & 31, oi = t >> 5;
#pragma unroll
    for (int rep = 0; rep < 4; rep++)
        T[oi + rep * 8][ci] = W[(size_t)(o0 + oi + rep * 8) * Cin + c0 + ci];
    __syncthreads();
    const int oi2 = t & 31, ci2 = t >> 5;
#pragma unroll
    for (int rep = 0; rep < 4; rep++)
        Wt[(size_t)(c0 + ci2 + rep * 8) * 256 + o0 + oi2] = T[oi2][ci2 + rep * 8];
}

// ---------------------------------------------------------------------------
// Split [4][256][256] (k-major) weights into h/m/l bf16 planes, PACKED
// interleaved in MFMA-B fragment order: fragment g=(l*8+ks)*16+nt, plane p:
// bf16x8 unit index (g*3+p)*64 + lane. Lane holds
// B[k=ks*32+(lane>>4)*8+j][n=nt*16+(lane&15)], j=0..7 (16B).
// Grid 128 x 256.
// ---------------------------------------------------------------------------
__global__ __launch_bounds__(256) void prep_wfrag3(
    const float* __restrict__ W, unsigned short* __restrict__ Wpk)
{
    const int t = threadIdx.x;
    const int g = blockIdx.x * 4 + (t >> 6);
    const int lane = t & 63;
    const int nt = g & 15, ks = (g >> 4) & 7, l = g >> 7;
    const int n = nt * 16 + (lane & 15);
    const int k0 = ks * 32 + (lane >> 4) * 8;
    unsigned short h[8], m[8], lo[8];
#pragma unroll
    for (int j = 0; j < 8; j++) {
        const float f = W[(size_t)l * 65536 + (size_t)(k0 + j) * 256 + n];
        h[j] = bf16_rn(f);
        const float r1 = f - bf16f(h[j]);
        m[j] = bf16_rn(r1);
        lo[j] = bf16_rn(r1 - bf16f(m[j]));
    }
    const size_t oh = ((size_t)(g * 3 + 0) * 64 + lane) * 8;
    const size_t om = ((size_t)(g * 3 + 1) * 64 + lane) * 8;
    const size_t ol = ((size_t)(g * 3 + 2) * 64 + lane) * 8;
#pragma unroll
    for (int j = 0; j < 8; j++) { Wpk[oh + j] = h[j]; Wpk[om + j] = m[j]; Wpk[ol + j] = lo[j]; }
}

// ---------------------------------------------------------------------------
// Lateral 1x1 conv + BN + transpose to flat (fp32 VALU, double-buffered DMA).
// ---------------------------------------------------------------------------
template<int PX, int OT, int RPT, int CHUNKS>
__global__ __launch_bounds__(256) void lateral_k(
    const float* __restrict__ x, const float* __restrict__ Wt,
    const float* __restrict__ bng, const float* __restrict__ bnb,
    const float* __restrict__ bnm, const float* __restrict__ bnv,
    float* __restrict__ flat, int HW, int base)
{
    constexpr int GO = OT / 4;
    constexpr int WI = OT / 32;
    constexpr int XI = PX / 8;
    __shared__ float Wc[2][32 * OT];
    __shared__ float sx[2][32 * PX];

    const int t = threadIdx.x, lane = t & 63, w = t >> 6;
    const int tc = t % GO;
    const int tr = t / GO;
    const int p0 = blockIdx.x * PX;
    const int b  = blockIdx.y;
    const int o0 = blockIdx.z * OT;
    const float* xb = x + (size_t)b * (CHUNKS * 32) * HW;

    float acc[RPT][4];
#pragma unroll
    for (int r = 0; r < RPT; r++)
#pragma unroll
        for (int c = 0; c < 4; c++) acc[r][c] = 0.0f;

    auto stage = [&](int ch, int buf) {
#pragma unroll
        for (int i = 0; i < WI; i++) {
            const int q = w * WI + i;
            const int f = q * 256 + lane * 4;
            const int kk = f / OT, col = f % OT;
            async_load16(&Wt[(size_t)(ch * 32 + kk) * 256 + o0 + col],
                         &Wc[buf][q * 256]);
        }
        if (w < XI) {
            const int f = w * 256 + lane * 4;
            const int kk = f / PX, col = f % PX;
            async_load16(&xb[(size_t)(ch * 32 + kk) * HW + p0 + col],
                         &sx[buf][w * 256]);
        }
    };

    stage(0, 0);
    for (int ch = 0; ch < CHUNKS; ch++) {
        __syncthreads();
        if (ch + 1 < CHUNKS) stage(ch + 1, (ch + 1) & 1);
        const float* Wb = Wc[ch & 1];
        const float* xv_ = sx[ch & 1];
#pragma unroll 8
        for (int kk = 0; kk < 32; kk++) {
            const float4 wv = *(const float4*)&Wb[kk * OT + tc * 4];
            float xv[RPT];
            if (RPT == 4) {
                const float4 xq = *(const float4*)&xv_[kk * PX + tr * 4];
                xv[0] = xq.x; xv[1] = xq.y; xv[2] = xq.z; xv[3] = xq.w;
            } else if (RPT == 2) {
                const float2 xq = *(const float2*)&xv_[kk * PX + tr * 2];
                xv[0] = xq.x; xv[1] = xq.y;
            } else {
                xv[0] = xv_[kk * PX + tr];
            }
#pragma unroll
            for (int r = 0; r < RPT; r++) {
                acc[r][0] += xv[r] * wv.x;
                acc[r][1] += xv[r] * wv.y;
                acc[r][2] += xv[r] * wv.z;
                acc[r][3] += xv[r] * wv.w;
            }
        }
    }

    const int o = o0 + tc * 4;
    const float4 gg = *(const float4*)&bng[o];
    const float4 bb = *(const float4*)&bnb[o];
    const float4 mm = *(const float4*)&bnm[o];
    const float4 vv = *(const float4*)&bnv[o];
    const float sc[4] = {gg.x * rsqrtf(vv.x + LN_EPS), gg.y * rsqrtf(vv.y + LN_EPS),
                         gg.z * rsqrtf(vv.z + LN_EPS), gg.w * rsqrtf(vv.w + LN_EPS)};
    const float mh[4] = {mm.x, mm.y, mm.z, mm.w};
    const float bh[4] = {bb.x, bb.y, bb.z, bb.w};

#pragma unroll
    for (int r = 0; r < RPT; r++) {
        const int p = p0 + tr * RPT + r;
        const size_t row = (size_t)b * 5376 + base + p;
        float4 outv;
        outv.x = (acc[r][0] - mh[0]) * sc[0] + bh[0];
        outv.y = (acc[r][1] - mh[1]) * sc[1] + bh[1];
        outv.z = (acc[r][2] - mh[2]) * sc[2] + bh[2];
        outv.w = (acc[r][3] - mh[3]) * sc[3] + bh[3];
        *(float4*)&flat[row * 256 + o] = outv;
    }
}

// ---------------------------------------------------------------------------
// bf16x3 MFMA layer core, 6 products (hh, hm, mh, mm, hl, lh).
// Product-major / nt-minor ordering: 8 independent acc chains.
// B loads batched (12 per ks) from the packed interleaved buffer.
// ---------------------------------------------------------------------------
__device__ __forceinline__ void mfma_layer3(
    const unsigned short* __restrict__ Wpk,
    int l, int w, int lane,
    const unsigned short* Xh, const unsigned short* Xm, const unsigned short* Xl,
    f32x4 acc[2][4])
{
    const bf16x8* BP = (const bf16x8*)Wpk;
#pragma unroll
    for (int mt = 0; mt < 2; mt++)
#pragma unroll
        for (int nt = 0; nt < 4; nt++) acc[mt][nt] = (f32x4){0.f, 0.f, 0.f, 0.f};
#pragma unroll
    for (int ks = 0; ks < 8; ks++) {
        const int ar = lane & 15;
        const int ao = ks * 32 + (lane >> 4) * 8;
        // batched B loads: 12 independent 16B global loads
        bf16x8 bh[4], bm[4], bl[4];
#pragma unroll
        for (int nt = 0; nt < 4; nt++) {
            const int g = (l * 8 + ks) * 16 + (w * 4 + nt);
            bh[nt] = BP[(g * 3 + 0) * 64 + lane];
            bm[nt] = BP[(g * 3 + 1) * 64 + lane];
            bl[nt] = BP[(g * 3 + 2) * 64 + lane];
        }
        const bf16x8 ah0 = *(const bf16x8*)&Xh[ar * XS + ao];
        const bf16x8 ah1 = *(const bf16x8*)&Xh[(ar + 16) * XS + ao];
        const bf16x8 am0 = *(const bf16x8*)&Xm[ar * XS + ao];
        const bf16x8 am1 = *(const bf16x8*)&Xm[(ar + 16) * XS + ao];
        const bf16x8 al0 = *(const bf16x8*)&Xl[ar * XS + ao];
        const bf16x8 al1 = *(const bf16x8*)&Xl[(ar + 16) * XS + ao];
        // product-major, nt-minor: consecutive MFMAs hit different accumulators
#pragma unroll
        for (int nt = 0; nt < 4; nt++) acc[0][nt] = __builtin_amdgcn_mfma_f32_16x16x32_bf16(ah0, bh[nt], acc[0][nt], 0, 0, 0);
#pragma unroll
        for (int nt = 0; nt < 4; nt++) acc[1][nt] = __builtin_amdgcn_mfma_f32_16x16x32_bf16(ah1, bh[nt], acc[1][nt], 0, 0, 0);
#pragma unroll
        for (int nt = 0; nt < 4; nt++) acc[0][nt] = __builtin_amdgcn_mfma_f32_16x16x32_bf16(ah0, bm[nt], acc[0][nt], 0, 0, 0);
#pragma unroll
        for (int nt = 0; nt < 4; nt++) acc[1][nt] = __builtin_amdgcn_mfma_f32_16x16x32_bf16(ah1, bm[nt], acc[1][nt], 0, 0, 0);
#pragma unroll
        for (int nt = 0; nt < 4; nt++) acc[0][nt] = __builtin_amdgcn_mfma_f32_16x16x32_bf16(am0, bh[nt], acc[0][nt], 0, 0, 0);
#pragma unroll
        for (int nt = 0; nt < 4; nt++) acc[1][nt] = __builtin_amdgcn_mfma_f32_16x16x32_bf16(am1, bh[nt], acc[1][nt], 0, 0, 0);
#pragma unroll
        for (int nt = 0; nt < 4; nt++) acc[0][nt] = __builtin_amdgcn_mfma_f32_16x16x32_bf16(am0, bm[nt], acc[0][nt], 0, 0, 0);
#pragma unroll
        for (int nt = 0; nt < 4; nt++) acc[1][nt] = __builtin_amdgcn_mfma_f32_16x16x32_bf16(am1, bm[nt], acc[1][nt], 0, 0, 0);
#pragma unroll
        for (int nt = 0; nt < 4; nt++) acc[0][nt] = __builtin_amdgcn_mfma_f32_16x16x32_bf16(ah0, bl[nt], acc[0][nt], 0, 0, 0);
#pragma unroll
        for (int nt = 0; nt < 4; nt++) acc[1][nt] = __builtin_amdgcn_mfma_f32_16x16x32_bf16(ah1, bl[nt], acc[1][nt], 0, 0, 0);
#pragma unroll
        for (int nt = 0; nt < 4; nt++) acc[0][nt] = __builtin_amdgcn_mfma_f32_16x16x32_bf16(al0, bh[nt], acc[0][nt], 0, 0, 0);
#pragma unroll
        for (int nt = 0; nt < 4; nt++) acc[1][nt] = __builtin_amdgcn_mfma_f32_16x16x32_bf16(al1, bh[nt], acc[1][nt], 0, 0, 0);
    }
}

// bias add + cross-wave LN stats (one internal __syncthreads).
__device__ __forceinline__ void ln_stats(
    f32x4 acc[2][4], const float* __restrict__ bias,
    int w, int lane, float* red, float mean[2][4], float rstd[2][4])
{
    const int colb = lane & 15;
    float bvs[4];
#pragma unroll
    for (int nt = 0; nt < 4; nt++) bvs[nt] = bias[w * 64 + nt * 16 + colb];
#pragma unroll
    for (int mt = 0; mt < 2; mt++)
#pragma unroll
        for (int nt = 0; nt < 4; nt++)
#pragma unroll
            for (int r = 0; r < 4; r++) acc[mt][nt][r] += bvs[nt];

#pragma unroll
    for (int mt = 0; mt < 2; mt++)
#pragma unroll
        for (int r = 0; r < 4; r++) {
            float s = acc[mt][0][r] + acc[mt][1][r] + acc[mt][2][r] + acc[mt][3][r];
            float ss = acc[mt][0][r] * acc[mt][0][r] + acc[mt][1][r] * acc[mt][1][r] +
                       acc[mt][2][r] * acc[mt][2][r] + acc[mt][3][r] * acc[mt][3][r];
#pragma unroll
            for (int off = 1; off < 16; off <<= 1) {
                s  += __shfl_xor(s, off, 64);
                ss += __shfl_xor(ss, off, 64);
            }
            if (colb == 0) {
                const int row = mt * 16 + (lane >> 4) * 4 + r;
                red[w * 64 + row] = s;
                red[256 + w * 64 + row] = ss;
            }
        }
    __syncthreads();
#pragma unroll
    for (int mt = 0; mt < 2; mt++)
#pragma unroll
        for (int r = 0; r < 4; r++) {
            const int row = mt * 16 + (lane >> 4) * 4 + r;
            const float s  = red[row] + red[64 + row] + red[128 + row] + red[192 + row];
            const float ss = red[256 + row] + red[320 + row] + red[384 + row] + red[448 + row];
            const float m = s * (1.0f / 256.0f);
            mean[mt][r] = m;
            rstd[mt][r] = rsqrtf(ss * (1.0f / 256.0f) - m * m + LN_EPS);
        }
}

// LN apply + SiLU + 3-way split back into X planes (wave-disjoint cols).
__device__ __forceinline__ void write_x3(
    f32x4 acc[2][4], const float mean[2][4], const float rstd[2][4],
    const float* __restrict__ g, const float* __restrict__ b,
    int w, int lane, unsigned short* Xh, unsigned short* Xm, unsigned short* Xl)
{
    const int colb = lane & 15;
#pragma unroll
    for (int nt = 0; nt < 4; nt++) {
        const int col = w * 64 + nt * 16 + colb;
        const float gc = g[col], bc = b[col];
#pragma unroll
        for (int mt = 0; mt < 2; mt++)
#pragma unroll
            for (int r = 0; r < 4; r++) {
                const int row = mt * 16 + (lane >> 4) * 4 + r;
                float v = (acc[mt][nt][r] - mean[mt][r]) * rstd[mt][r] * gc + bc;
                v = v * sigmoidf(v);
                const unsigned short h = bf16_rn(v);
                const float r1 = v - bf16f(h);
                const unsigned short m = bf16_rn(r1);
                Xh[row * XS + col] = h;
                Xm[row * XS + col] = m;
                Xl[row * XS + col] = bf16_rn(r1 - bf16f(m));
            }
    }
}

// ---------------------------------------------------------------------------
// Fused loc MLP (bf16x3 MFMA): 4 layers + fused 256->1 projection. Grid M/32.
// LDS: 3 X planes (stride 264) + red = ~52 KB -> 3 blocks/CU.
// ---------------------------------------------------------------------------
__global__ __launch_bounds__(256, 3) void loc_mlp_mfma3(
    const float* __restrict__ Xin,
    const unsigned short* __restrict__ Wpk,
    const float* __restrict__ bs, const float* __restrict__ lng,
    const float* __restrict__ lnb, const float* __restrict__ Wf,
    const float* __restrict__ bfp, float* __restrict__ logits)
{
    __shared__ unsigned short Xh[32 * XS];
    __shared__ unsigned short Xm[32 * XS];
    __shared__ unsigned short Xl[32 * XS];
    __shared__ float red[512];
    const int t = threadIdx.x, lane = t & 63, w = t >> 6;
    const int r0 = blockIdx.x * 32;

    const float* Xg = Xin + (size_t)r0 * 256;
#pragma unroll
    for (int i = 0; i < 8; i++) {
        const int f = i * 1024 + t * 4;
        const int row = f >> 8, col = f & 255;
        const float4 v = *(const float4*)&Xg[f];
        ushort4 h, m, lo;
        h.x = bf16_rn(v.x); { float r1 = v.x - bf16f(h.x); m.x = bf16_rn(r1); lo.x = bf16_rn(r1 - bf16f(m.x)); }
        h.y = bf16_rn(v.y); { float r1 = v.y - bf16f(h.y); m.y = bf16_rn(r1); lo.y = bf16_rn(r1 - bf16f(m.y)); }
        h.z = bf16_rn(v.z); { float r1 = v.z - bf16f(h.z); m.z = bf16_rn(r1); lo.z = bf16_rn(r1 - bf16f(m.z)); }
        h.w = bf16_rn(v.w); { float r1 = v.w - bf16f(h.w); m.w = bf16_rn(r1); lo.w = bf16_rn(r1 - bf16f(m.w)); }
        *(ushort4*)&Xh[row * XS + col] = h;
        *(ushort4*)&Xm[row * XS + col] = m;
        *(ushort4*)&Xl[row * XS + col] = lo;
    }

    f32x4 acc[2][4];
    float mean[2][4], rstd[2][4];
    for (int l = 0; l < 4; l++) {
        __syncthreads();                      // X ready
        mfma_layer3(Wpk, l, w, lane, Xh, Xm, Xl, acc);
        ln_stats(acc, bs + l * 256, w, lane, red, mean, rstd);
        if (l < 3) {
            write_x3(acc, mean, rstd, lng + l * 256, lnb + l * 256, w, lane, Xh, Xm, Xl);
        } else {
            const int colb = lane & 15;
            float p[2][4];
#pragma unroll
            for (int mt = 0; mt < 2; mt++)
#pragma unroll
                for (int r = 0; r < 4; r++) p[mt][r] = 0.0f;
#pragma unroll
            for (int nt = 0; nt < 4; nt++) {
                const int col = w * 64 + nt * 16 + colb;
                const float gc = lng[3 * 256 + col], bc = lnb[3 * 256 + col];
                const float wf = Wf[col];
#pragma unroll
                for (int mt = 0; mt < 2; mt++)
#pragma unroll
                    for (int r = 0; r < 4; r++) {
                        float v = (acc[mt][nt][r] - mean[mt][r]) * rstd[mt][r] * gc + bc;
                        p[mt][r] += (v * sigmoidf(v)) * wf;
                    }
            }
            __syncthreads();
#pragma unroll
            for (int mt = 0; mt < 2; mt++)
#pragma unroll
                for (int r = 0; r < 4; r++) {
                    float s = p[mt][r];
#pragma unroll
                    for (int off = 1; off < 16; off <<= 1) s += __shfl_xor(s, off, 64);
                    if (colb == 0)
                        red[w * 64 + mt * 16 + (lane >> 4) * 4 + r] = s;
                }
            __syncthreads();
            if (t < 32)
                logits[r0 + t] = red[t] + red[64 + t] + red[128 + t] + red[192 + t] + bfp[0];
        }
    }
}

// ---------------------------------------------------------------------------
// Top-100 per batch (sorted desc, ties -> lower index). Grid B, block 256.
// ---------------------------------------------------------------------------
__global__ __launch_bounds__(256) void topk_kernel(
    const float* __restrict__ logits, int* __restrict__ idx_out,
    float* __restrict__ out, int B)
{
    __shared__ float v[5376];
    __shared__ float wv_s[4];
    __shared__ int wi_s[4];

    const int t = threadIdx.x, b = blockIdx.x;
    const int lane = t & 63, w = t >> 6;

    for (int i = t; i < 5376; i += 256) v[i] = logits[b * 5376 + i];
    __syncthreads();

    int cnt = 0;
    for (int k = 0; k < 100; k++) {
        float bv = -1e30f;
        int bi = 0x7fffffff;
        for (int i = t; i < 5376; i += 256) {
            const float val = v[i];
            if (val > bv) { bv = val; bi = i; }
        }
#pragma unroll
        for (int off = 32; off > 0; off >>= 1) {
            const float ov = __shfl_xor(bv, off, 64);
            const int oi = __shfl_xor(bi, off, 64);
            if (ov > bv || (ov == bv && oi < bi)) { bv = ov; bi = oi; }
        }
        if (lane == 0) { wv_s[w] = bv; wi_s[w] = bi; }
        __syncthreads();
        if (t == 0) {
            float fb = wv_s[0]; int fi = wi_s[0];
            for (int q = 1; q < 4; q++)
                if (wv_s[q] > fb || (wv_s[q] == fb && wi_s[q] < fi)) { fb = wv_s[q]; fi = wi_s[q]; }
            v[fi] = -1e30f;
            idx_out[b * 100 + k] = fi;
            out[B + b * 100 + k] = sigmoidf(fb);
            if (fb > 0.0f) cnt++;
        }
        __syncthreads();
    }
    if (t == 0) out[b] = (float)cnt;
}

// ---------------------------------------------------------------------------
// fp32 GEMM+bias+LN-stats on the wave-private 32x256 LDS tile (R3 core).
// ---------------------------------------------------------------------------
__device__ __forceinline__ void gemm8_pipelined(
    const float* __restrict__ Wg, const float* __restrict__ bias,
    float* X, float (*Wbuf)[8 * 256], int t,
    float acc[8][4], float mean[8], float rstd[8])
{
    const int lane = t & 63, w = t >> 6;
#pragma unroll
    for (int mi = 0; mi < 8; mi++)
#pragma unroll
        for (int c = 0; c < 4; c++) acc[mi][c] = 0.0f;

#pragma unroll
    for (int i = 0; i < 2; i++) {
        const int q = w * 2 + i;
        async_load16(&Wg[(size_t)q * 256 + lane * 4], &Wbuf[0][q * 256]);
    }

    for (int ch = 0; ch < 32; ch++) {
        __syncthreads();
        if (ch + 1 < 32) {
#pragma unroll
            for (int i = 0; i < 2; i++) {
                const int q = w * 2 + i;
                async_load16(&Wg[(size_t)((ch + 1) * 8 + q) * 256 + lane * 4],
                             &Wbuf[(ch + 1) & 1][q * 256]);
            }
        }
        const float* Wb = Wbuf[ch & 1];
#pragma unroll
        for (int k4 = 0; k4 < 2; k4++) {
            float4 xq[8];
#pragma unroll
            for (int mi = 0; mi < 8; mi++)
                xq[mi] = *(const float4*)&X[(w * 8 + mi) * 256 + ch * 8 + k4 * 4];
#pragma unroll
            for (int j = 0; j < 4; j++) {
                const float4 wv = *(const float4*)&Wb[(k4 * 4 + j) * 256 + lane * 4];
#pragma unroll
                for (int mi = 0; mi < 8; mi++) {
                    const float xs = (j == 0) ? xq[mi].x : (j == 1) ? xq[mi].y
                                   : (j == 2) ? xq[mi].z : xq[mi].w;
                    acc[mi][0] += xs * wv.x;
                    acc[mi][1] += xs * wv.y;
                    acc[mi][2] += xs * wv.z;
                    acc[mi][3] += xs * wv.w;
                }
            }
        }
    }

    const int o = lane * 4;
    const float4 bv = *(const float4*)&bias[o];
#pragma unroll
    for (int mi = 0; mi < 8; mi++) {
        acc[mi][0] += bv.x; acc[mi][1] += bv.y; acc[mi][2] += bv.z; acc[mi][3] += bv.w;
        float s  = acc[mi][0] + acc[mi][1] + acc[mi][2] + acc[mi][3];
        float ss = acc[mi][0] * acc[mi][0] + acc[mi][1] * acc[mi][1] +
                   acc[mi][2] * acc[mi][2] + acc[mi][3] * acc[mi][3];
        s  = wave_sum(s);
        ss = wave_sum(ss);
        const float m = s * (1.0f / 256.0f);
        mean[mi] = m;
        rstd[mi] = rsqrtf(ss * (1.0f / 256.0f) - m * m + LN_EPS);
    }
}

// ---------------------------------------------------------------------------
// Fused heads (fp32, proven): gather + 4 layers + finals. Grid (25,2).
// ---------------------------------------------------------------------------
__global__ __launch_bounds__(256) void heads_mlp(
    const float* __restrict__ flat, const int* __restrict__ idxb,
    const float* __restrict__ cWs, const float* __restrict__ cbs,
    const float* __restrict__ cg, const float* __restrict__ cb,
    const float* __restrict__ cWf, const float* __restrict__ cbf,
    const float* __restrict__ xWs, const float* __restrict__ xbs,
    const float* __restrict__ xg, const float* __restrict__ xb_,
    const float* __restrict__ xWf, const float* __restrict__ xbf,
    const int* __restrict__ full_h, const int* __restrict__ full_w,
    float* __restrict__ out, int B)
{
    __shared__ float X[32 * 256];
    __shared__ float Wbuf[2][8 * 256];
    const int head = blockIdx.y;
    const float* Ws  = head ? xWs : cWs;
    const float* bsv = head ? xbs : cbs;
    const float* gv_ = head ? xg  : cg;
    const float* bv_ = head ? xb_ : cb;

    const int t = threadIdx.x, lane = t & 63, w = t >> 6;
    const int r0 = blockIdx.x * 32;

#pragma unroll
    for (int i = 0; i < 8; i++) {
        const int r = r0 + w * 8 + i;
        const int n = idxb[r];
        const int b = r / 100;
        *(float4*)&X[(w * 8 + i) * 256 + lane * 4] =
            *(const float4*)&flat[((size_t)b * 5376 + n) * 256 + lane * 4];
    }

    float acc[8][4], mean[8], rstd[8];
    for (int l = 0; l < 4; l++) {
        gemm8_pipelined(Ws + l * 65536, bsv + l * 256, X, Wbuf, t, acc, mean, rstd);
        const int o = lane * 4;
        const float4 gvv = *(const float4*)&gv_[l * 256 + o];
        const float4 bvv = *(const float4*)&bv_[l * 256 + o];
        const float gl[4] = {gvv.x, gvv.y, gvv.z, gvv.w};
        const float bl[4] = {bvv.x, bvv.y, bvv.z, bvv.w};
#pragma unroll
        for (int mi = 0; mi < 8; mi++) {
            float4 outv;
            float v0 = (acc[mi][0] - mean[mi]) * rstd[mi] * gl[0] + bl[0];
            float v1 = (acc[mi][1] - mean[mi]) * rstd[mi] * gl[1] + bl[1];
            float v2 = (acc[mi][2] - mean[mi]) * rstd[mi] * gl[2] + bl[2];
            float v3 = (acc[mi][3] - mean[mi]) * rstd[mi] * gl[3] + bl[3];
            outv.x = v0 * sigmoidf(v0); outv.y = v1 * sigmoidf(v1);
            outv.z = v2 * sigmoidf(v2); outv.w = v3 * sigmoidf(v3);
            *(float4*)&X[(w * 8 + mi) * 256 + o] = outv;
        }
    }
    __syncthreads();

    const int m = t >> 3, g = t & 7;
    if (head == 0) {
        const int jbase = g * 10;
        float lg[10];
#pragma unroll
        for (int jj = 0; jj < 10; jj++) lg[jj] = cbf[jbase + jj];
        for (int k = 0; k < 256; k++) {
            const float hv = X[m * 256 + k];
            const float* wr = &cWf[k * 80 + jbase];
#pragma unroll
            for (int jj = 0; jj < 10; jj++) lg[jj] += hv * wr[jj];
        }
        float best = lg[0]; int bj = jbase;
#pragma unroll
        for (int jj = 1; jj < 10; jj++)
            if (lg[jj] > best) { best = lg[jj]; bj = jbase + jj; }
#pragma unroll
        for (int off = 1; off < 8; off <<= 1) {
            const float ob = __shfl_xor(best, off, 64);
            const int oj = __shfl_xor(bj, off, 64);
            if (ob > best || (ob == best && oj < bj)) { best = ob; bj = oj; }
        }
        if (g == 0) out[B + B * 100 + r0 + m] = (float)bj;
    } else {
        float a[4] = {0.f, 0.f, 0.f, 0.f};
#pragma unroll
        for (int k4 = 0; k4 < 8; k4++) {
            const float4 hv = *(const float4*)&X[m * 256 + g * 32 + k4 * 4];
            const float h4[4] = {hv.x, hv.y, hv.z, hv.w};
#pragma unroll
            for (int j = 0; j < 4; j++) {
                const int k = g * 32 + k4 * 4 + j;
                const float4 wf = *(const float4*)&xWf[k * 4];
                a[0] += h4[j] * wf.x; a[1] += h4[j] * wf.y;
                a[2] += h4[j] * wf.z; a[3] += h4[j] * wf.w;
            }
        }
#pragma unroll
        for (int off = 1; off < 8; off <<= 1) {
            a[0] += __shfl_xor(a[0], off, 64);
            a[1] += __shfl_xor(a[1], off, 64);
            a[2] += __shfl_xor(a[2], off, 64);
            a[3] += __shfl_xor(a[3], off, 64);
        }
        if (g == 0) {
            const int r = r0 + m;
            const float e0 = a[0] + xbf[0], e1 = a[1] + xbf[1];
            const float e2 = a[2] + xbf[2], e3 = a[3] + xbf[3];
            const int n = idxb[r];
            int base, gw, gh;
            if (n < 4096)      { base = 0;    gw = 64; gh = 64; }
            else if (n < 5120) { base = 4096; gw = 32; gh = 32; }
            else               { base = 5120; gw = 16; gh = 16; }
            const int p = n - base;
            const int py = p / gw, px = p % gw;
            const float gx = (px + 0.5f) / gw;
            const float gy = (py + 0.5f) / gh;
            const float fw = (float)full_w[0], fh = (float)full_h[0];
            const int ob = B + 2 * B * 100;
            out[ob + r * 4 + 0] = (gx - 0.5f / gw * expf(e0)) * fw;
            out[ob + r * 4 + 1] = (gy - 0.5f / gh * expf(e1)) * fh;
            out[ob + r * 4 + 2] = (gx + 0.5f / gw * expf(e2)) * fw;
            out[ob + r * 4 + 3] = (gy + 0.5f / gh * expf(e3)) * fh;
        }
    }
}

extern "C" void kernel_launch(void* const* d_in, const int* in_sizes, int n_in,
                              void* d_out, int out_size, void* d_ws, size_t ws_size,
                              hipStream_t stream)
{
    const float* x3  = (const float*)d_in[0];
    const float* x4  = (const float*)d_in[1];
    const float* x5  = (const float*)d_in[2];
    const float* lw3 = (const float*)d_in[3];
    const float* lw4 = (const float*)d_in[4];
    const float* lw5 = (const float*)d_in[5];
    const float* bng = (const float*)d_in[6];
    const float* bnb = (const float*)d_in[7];
    const float* bnm = (const float*)d_in[8];
    const float* bnv = (const float*)d_in[9];

    const float* loc_Ws  = (const float*)d_in[10];
    const float* loc_bs  = (const float*)d_in[11];
    const float* loc_lng = (const float*)d_in[12];
    const float* loc_lnb = (const float*)d_in[13];
    const float* loc_Wf  = (const float*)d_in[14];
    const float* loc_bf  = (const float*)d_in[15];

    const float* cls_Ws  = (const float*)d_in[16];
    const float* cls_bs  = (const float*)d_in[17];
    const float* cls_lng = (const float*)d_in[18];
    const float* cls_lnb = (const float*)d_in[19];
    const float* cls_Wf  = (const float*)d_in[20];
    const float* cls_bf  = (const float*)d_in[21];

    const float* box_Ws  = (const float*)d_in[22];
    const float* box_bs  = (const float*)d_in[23];
    const float* box_lng = (const float*)d_in[24];
    const float* box_lnb = (const float*)d_in[25];
    const float* box_Wf  = (const float*)d_in[26];
    const float* box_bf  = (const float*)d_in[27];

    const int* full_h = (const int*)d_in[28];
    const int* full_w = (const int*)d_in[29];

    const int B = in_sizes[0] / (256 * 64 * 64);   // 8
    const int M = B * 5376;                        // 43008

    float* ws = (float*)d_ws;
    float* flat = ws;                                  // [M*256]
    float* loc  = flat + (size_t)M * 256;              // [M]
    int*   idxb = (int*)(loc + M);                     // [B*100] (padded 1024)
    float* Wt3  = (float*)(idxb + 1024);               // [256*256]
    float* Wt4  = Wt3 + 256 * 256;                     // [512*256]
    float* Wt5  = Wt4 + 512 * 256;                     // [1024*256]
    unsigned short* locWpk = (unsigned short*)(Wt5 + 1024 * 256);  // 3*4*8*16*64*8

    float* out = (float*)d_out;
    const dim3 blk(256);

    // 0) weight preprocessing
    transpose_w<<<dim3(256 / 32, 8), blk, 0, stream>>>(lw3, Wt3, 256);
    transpose_w<<<dim3(512 / 32, 8), blk, 0, stream>>>(lw4, Wt4, 512);
    transpose_w<<<dim3(1024 / 32, 8), blk, 0, stream>>>(lw5, Wt5, 1024);
    prep_wfrag3<<<128, blk, 0, stream>>>(loc_Ws, locWpk);

    // 1) laterals -> flat
    lateral_k<32, 128, 4, 8 ><<<dim3(128, B, 2), blk, 0, stream>>>(x3, Wt3, bng + 0,   bnb + 0,   bnm + 0,   bnv + 0,   flat, 4096, 0);
    lateral_k<32, 64,  2, 16><<<dim3(32,  B, 4), blk, 0, stream>>>(x4, Wt4, bng + 256, bnb + 256, bnm + 256, bnv + 256, flat, 1024, 4096);
    lateral_k<16, 64,  1, 32><<<dim3(16,  B, 4), blk, 0, stream>>>(x5, Wt5, bng + 512, bnb + 512, bnm + 512, bnv + 512, flat, 256,  5120);

    // 2) fused loc MLP (bf16x3 MFMA) -> logits
    loc_mlp_mfma3<<<M / 32, blk, 0, stream>>>(flat, locWpk, loc_bs,
                                              loc_lng, loc_lnb, loc_Wf, loc_bf, loc);

    // 3) top-k
    topk_kernel<<<B, blk, 0, stream>>>(loc, idxb, out, B);

    // 4) both heads (fp32, proven)
    heads_mlp<<<dim3((B * 100) / 32, 2), blk, 0, stream>>>(
        flat, idxb,
        cls_Ws, cls_bs, cls_lng, cls_lnb, cls_Wf, cls_bf,
        box_Ws, box_bs, box_lng, box_lnb, box_Wf, box_bf,
        full_h, full_w, out, B);
}

// Round 8
// 735.052 us; speedup vs baseline: 2.2444x; 1.2533x over previous
//
#include <hip/hip_runtime.h>
#include <math.h>

#define LN_EPS 1e-5f
#define XS2 264   // padded X row stride in halves (132 dwords ≡ 4 mod 32 banks)

typedef __attribute__((ext_vector_type(8))) _Float16 f16x8;
typedef __attribute__((ext_vector_type(4))) _Float16 f16x4;
typedef __attribute__((ext_vector_type(4))) float f32x4;

__device__ __forceinline__ float sigmoidf(float x) { return 1.0f / (1.0f + expf(-x)); }

__device__ __forceinline__ float wave_sum(float v) {
    v += __shfl_xor(v, 32, 64);
    v += __shfl_xor(v, 16, 64);
    v += __shfl_xor(v, 8, 64);
    v += __shfl_xor(v, 4, 64);
    v += __shfl_xor(v, 2, 64);
    v += __shfl_xor(v, 1, 64);
    return v;
}

// async global->LDS DMA, 16B per lane (wave-uniform lds base, lane i -> +16i)
__device__ __forceinline__ void async_load16(const void* g, void* l) {
    __builtin_amdgcn_global_load_lds(
        (const __attribute__((address_space(1))) void*)g,
        (__attribute__((address_space(3))) void*)l, 16, 0, 0);
}

// ---------------------------------------------------------------------------
// W [256][Cin] -> Wt [Cin][256]. Grid (Cin/32, 256/32), block 256.
// ---------------------------------------------------------------------------
__global__ __launch_bounds__(256) void transpose_w(
    const float* __restrict__ W, float* __restrict__ Wt, int Cin)
{
    __shared__ float T[32][33];
    const int c0 = blockIdx.x * 32, o0 = blockIdx.y * 32;
    const int t = threadIdx.x;
    const int ci = t & 31, oi = t >> 5;
#pragma unroll
    for (int rep = 0; rep < 4; rep++)
        T[oi + rep * 8][ci] = W[(size_t)(o0 + oi + rep * 8) * Cin + c0 + ci];
    __syncthreads();
    const int oi2 = t & 31, ci2 = t >> 5;
#pragma unroll
    for (int rep = 0; rep < 4; rep++)
        Wt[(size_t)(c0 + ci2 + rep * 8) * 256 + o0 + oi2] = T[oi2][ci2 + rep * 8];
}

// ---------------------------------------------------------------------------
// Split [4][256][256] (k-major) weights into hi/lo fp16 planes, packed
// interleaved in MFMA-B fragment order: frag g=(l*8+ks)*16+nt, plane p in
// {0,1}: f16x8 unit (g*2+p)*64+lane. Lane holds
// B[k=ks*32+(lane>>4)*8+j][n=nt*16+(lane&15)], j=0..7 (16B). Grid 128 x 256.
// ---------------------------------------------------------------------------
__global__ __launch_bounds__(256) void prep_wfrag16(
    const float* __restrict__ W, _Float16* __restrict__ Wpk)
{
    const int t = threadIdx.x;
    const int g = blockIdx.x * 4 + (t >> 6);
    const int lane = t & 63;
    const int nt = g & 15, ks = (g >> 4) & 7, l = g >> 7;
    const int n = nt * 16 + (lane & 15);
    const int k0 = ks * 32 + (lane >> 4) * 8;
    _Float16 h[8], m[8];
#pragma unroll
    for (int j = 0; j < 8; j++) {
        const float f = W[(size_t)l * 65536 + (size_t)(k0 + j) * 256 + n];
        h[j] = (_Float16)f;
        m[j] = (_Float16)(f - (float)h[j]);
    }
    const size_t oh = ((size_t)(g * 2 + 0) * 64 + lane) * 8;
    const size_t om = ((size_t)(g * 2 + 1) * 64 + lane) * 8;
#pragma unroll
    for (int j = 0; j < 8; j++) { Wpk[oh + j] = h[j]; Wpk[om + j] = m[j]; }
}

// ---------------------------------------------------------------------------
// Lateral 1x1 conv + BN + transpose to flat (fp32 VALU, double-buffered DMA).
// ---------------------------------------------------------------------------
template<int PX, int OT, int RPT, int CHUNKS>
__global__ __launch_bounds__(256) void lateral_k(
    const float* __restrict__ x, const float* __restrict__ Wt,
    const float* __restrict__ bng, const float* __restrict__ bnb,
    const float* __restrict__ bnm, const float* __restrict__ bnv,
    float* __restrict__ flat, int HW, int base)
{
    constexpr int GO = OT / 4;
    constexpr int WI = OT / 32;
    constexpr int XI = PX / 8;
    __shared__ float Wc[2][32 * OT];
    __shared__ float sx[2][32 * PX];

    const int t = threadIdx.x, lane = t & 63, w = t >> 6;
    const int tc = t % GO;
    const int tr = t / GO;
    const int p0 = blockIdx.x * PX;
    const int b  = blockIdx.y;
    const int o0 = blockIdx.z * OT;
    const float* xb = x + (size_t)b * (CHUNKS * 32) * HW;

    float acc[RPT][4];
#pragma unroll
    for (int r = 0; r < RPT; r++)
#pragma unroll
        for (int c = 0; c < 4; c++) acc[r][c] = 0.0f;

    auto stage = [&](int ch, int buf) {
#pragma unroll
        for (int i = 0; i < WI; i++) {
            const int q = w * WI + i;
            const int f = q * 256 + lane * 4;
            const int kk = f / OT, col = f % OT;
            async_load16(&Wt[(size_t)(ch * 32 + kk) * 256 + o0 + col],
                         &Wc[buf][q * 256]);
        }
        if (w < XI) {
            const int f = w * 256 + lane * 4;
            const int kk = f / PX, col = f % PX;
            async_load16(&xb[(size_t)(ch * 32 + kk) * HW + p0 + col],
                         &sx[buf][w * 256]);
        }
    };

    stage(0, 0);
    for (int ch = 0; ch < CHUNKS; ch++) {
        __syncthreads();
        if (ch + 1 < CHUNKS) stage(ch + 1, (ch + 1) & 1);
        const float* Wb = Wc[ch & 1];
        const float* xv_ = sx[ch & 1];
#pragma unroll 8
        for (int kk = 0; kk < 32; kk++) {
            const float4 wv = *(const float4*)&Wb[kk * OT + tc * 4];
            float xv[RPT];
            if (RPT == 4) {
                const float4 xq = *(const float4*)&xv_[kk * PX + tr * 4];
                xv[0] = xq.x; xv[1] = xq.y; xv[2] = xq.z; xv[3] = xq.w;
            } else if (RPT == 2) {
                const float2 xq = *(const float2*)&xv_[kk * PX + tr * 2];
                xv[0] = xq.x; xv[1] = xq.y;
            } else {
                xv[0] = xv_[kk * PX + tr];
            }
#pragma unroll
            for (int r = 0; r < RPT; r++) {
                acc[r][0] += xv[r] * wv.x;
                acc[r][1] += xv[r] * wv.y;
                acc[r][2] += xv[r] * wv.z;
                acc[r][3] += xv[r] * wv.w;
            }
        }
    }

    const int o = o0 + tc * 4;
    const float4 gg = *(const float4*)&bng[o];
    const float4 bb = *(const float4*)&bnb[o];
    const float4 mm = *(const float4*)&bnm[o];
    const float4 vv = *(const float4*)&bnv[o];
    const float sc[4] = {gg.x * rsqrtf(vv.x + LN_EPS), gg.y * rsqrtf(vv.y + LN_EPS),
                         gg.z * rsqrtf(vv.z + LN_EPS), gg.w * rsqrtf(vv.w + LN_EPS)};
    const float mh[4] = {mm.x, mm.y, mm.z, mm.w};
    const float bh[4] = {bb.x, bb.y, bb.z, bb.w};

#pragma unroll
    for (int r = 0; r < RPT; r++) {
        const int p = p0 + tr * RPT + r;
        const size_t row = (size_t)b * 5376 + base + p;
        float4 outv;
        outv.x = (acc[r][0] - mh[0]) * sc[0] + bh[0];
        outv.y = (acc[r][1] - mh[1]) * sc[1] + bh[1];
        outv.z = (acc[r][2] - mh[2]) * sc[2] + bh[2];
        outv.w = (acc[r][3] - mh[3]) * sc[3] + bh[3];
        *(float4*)&flat[row * 256 + o] = outv;
    }
}

// ---------------------------------------------------------------------------
// Fused loc MLP (fp16x2 MFMA, 4 products): 4 layers + 256->1 projection.
// Grid M/64, block 512 (8 waves). Wave w owns all 64 rows x cols
// [w*32, w*32+32). Each B fragment feeds 4 MFMAs (mt=0..3).
// LDS: 2 fp16 X planes (stride 264) 67.6KB + red 4KB -> 2 blocks/CU.
// ---------------------------------------------------------------------------
__global__ __launch_bounds__(512) void loc_mlp_f16(
    const float* __restrict__ Xin,
    const _Float16* __restrict__ Wpk,
    const float* __restrict__ bs, const float* __restrict__ lng,
    const float* __restrict__ lnb, const float* __restrict__ Wf,
    const float* __restrict__ bfp, float* __restrict__ logits)
{
    __shared__ _Float16 Xh[64 * XS2];
    __shared__ _Float16 Xm[64 * XS2];
    __shared__ float red[2 * 64 * 8];    // [plane][row][wave]
    const int t = threadIdx.x, lane = t & 63, w = t >> 6;
    const int r0 = blockIdx.x * 64;
    const f16x8* BP = (const f16x8*)Wpk;

    // stage 64x256 fp32 -> hi/lo fp16 planes (nontemporal: stream, don't evict W)
    const float* Xg = Xin + (size_t)r0 * 256;
#pragma unroll
    for (int i = 0; i < 8; i++) {
        const int f = i * 2048 + t * 4;
        const int row = f >> 8, col = f & 255;
        const f32x4 v = __builtin_nontemporal_load((const f32x4*)&Xg[f]);
        f16x4 h, m;
        h[0] = (_Float16)v[0]; m[0] = (_Float16)(v[0] - (float)h[0]);
        h[1] = (_Float16)v[1]; m[1] = (_Float16)(v[1] - (float)h[1]);
        h[2] = (_Float16)v[2]; m[2] = (_Float16)(v[2] - (float)h[2]);
        h[3] = (_Float16)v[3]; m[3] = (_Float16)(v[3] - (float)h[3]);
        *(f16x4*)&Xh[row * XS2 + col] = h;
        *(f16x4*)&Xm[row * XS2 + col] = m;
    }

    f32x4 acc[4][2];
    float mean[4][4], rstd[4][4];
    const int ar = lane & 15, quad = lane >> 4;

    for (int l = 0; l < 4; l++) {
        __syncthreads();                      // X planes ready
        // ---- GEMM: 4 products hh, hm, mh, mm ----
#pragma unroll
        for (int mt = 0; mt < 4; mt++)
#pragma unroll
            for (int q = 0; q < 2; q++) acc[mt][q] = (f32x4){0.f, 0.f, 0.f, 0.f};
#pragma unroll
        for (int ks = 0; ks < 8; ks++) {
            const int ao = ks * 32 + quad * 8;
            f16x8 bh[2], bm[2];
#pragma unroll
            for (int q = 0; q < 2; q++) {
                const int g = (l * 8 + ks) * 16 + (w * 2 + q);
                bh[q] = BP[(g * 2 + 0) * 64 + lane];
                bm[q] = BP[(g * 2 + 1) * 64 + lane];
            }
            f16x8 ah[4], am[4];
#pragma unroll
            for (int mt = 0; mt < 4; mt++) {
                ah[mt] = *(const f16x8*)&Xh[(ar + mt * 16) * XS2 + ao];
                am[mt] = *(const f16x8*)&Xm[(ar + mt * 16) * XS2 + ao];
            }
            // product-major, mt-minor: 8 independent chains per product pass
#pragma unroll
            for (int q = 0; q < 2; q++)
#pragma unroll
                for (int mt = 0; mt < 4; mt++)
                    acc[mt][q] = __builtin_amdgcn_mfma_f32_16x16x32_f16(ah[mt], bh[q], acc[mt][q], 0, 0, 0);
#pragma unroll
            for (int q = 0; q < 2; q++)
#pragma unroll
                for (int mt = 0; mt < 4; mt++)
                    acc[mt][q] = __builtin_amdgcn_mfma_f32_16x16x32_f16(ah[mt], bm[q], acc[mt][q], 0, 0, 0);
#pragma unroll
            for (int q = 0; q < 2; q++)
#pragma unroll
                for (int mt = 0; mt < 4; mt++)
                    acc[mt][q] = __builtin_amdgcn_mfma_f32_16x16x32_f16(am[mt], bh[q], acc[mt][q], 0, 0, 0);
#pragma unroll
            for (int q = 0; q < 2; q++)
#pragma unroll
                for (int mt = 0; mt < 4; mt++)
                    acc[mt][q] = __builtin_amdgcn_mfma_f32_16x16x32_f16(am[mt], bm[q], acc[mt][q], 0, 0, 0);
        }

        // ---- bias + LN stats (cross-wave over 8 col-waves) ----
        float bcol[2];
#pragma unroll
        for (int q = 0; q < 2; q++) bcol[q] = bs[l * 256 + (w * 2 + q) * 16 + ar];
#pragma unroll
        for (int mt = 0; mt < 4; mt++)
#pragma unroll
            for (int q = 0; q < 2; q++)
#pragma unroll
                for (int r = 0; r < 4; r++) acc[mt][q][r] += bcol[q];

#pragma unroll
        for (int mt = 0; mt < 4; mt++)
#pragma unroll
            for (int r = 0; r < 4; r++) {
                float s  = acc[mt][0][r] + acc[mt][1][r];
                float ss = acc[mt][0][r] * acc[mt][0][r] + acc[mt][1][r] * acc[mt][1][r];
#pragma unroll
                for (int off = 1; off < 16; off <<= 1) {
                    s  += __shfl_xor(s, off, 64);
                    ss += __shfl_xor(ss, off, 64);
                }
                if (ar == 0) {
                    const int row = mt * 16 + quad * 4 + r;
                    red[row * 8 + w] = s;
                    red[512 + row * 8 + w] = ss;
                }
            }
        __syncthreads();
#pragma unroll
        for (int mt = 0; mt < 4; mt++)
#pragma unroll
            for (int r = 0; r < 4; r++) {
                const int row = mt * 16 + quad * 4 + r;
                float s = 0.f, ss = 0.f;
#pragma unroll
                for (int q = 0; q < 8; q++) { s += red[row * 8 + q]; ss += red[512 + row * 8 + q]; }
                const float mn = s * (1.0f / 256.0f);
                mean[mt][r] = mn;
                rstd[mt][r] = rsqrtf(ss * (1.0f / 256.0f) - mn * mn + LN_EPS);
            }

        if (l < 3) {
            // ---- LN apply + SiLU + fp16x2 split back (wave-disjoint cols) ----
#pragma unroll
            for (int q = 0; q < 2; q++) {
                const int col = (w * 2 + q) * 16 + ar;
                const float gc = lng[l * 256 + col], bc = lnb[l * 256 + col];
#pragma unroll
                for (int mt = 0; mt < 4; mt++)
#pragma unroll
                    for (int r = 0; r < 4; r++) {
                        const int row = mt * 16 + quad * 4 + r;
                        float v = (acc[mt][q][r] - mean[mt][r]) * rstd[mt][r] * gc + bc;
                        v = v * sigmoidf(v);
                        const _Float16 h = (_Float16)v;
                        Xh[row * XS2 + col] = h;
                        Xm[row * XS2 + col] = (_Float16)(v - (float)h);
                    }
            }
        } else {
            // ---- fused 256->1 projection ----
            float p[4][4];
#pragma unroll
            for (int mt = 0; mt < 4; mt++)
#pragma unroll
                for (int r = 0; r < 4; r++) p[mt][r] = 0.0f;
#pragma unroll
            for (int q = 0; q < 2; q++) {
                const int col = (w * 2 + q) * 16 + ar;
                const float gc = lng[3 * 256 + col], bc = lnb[3 * 256 + col];
                const float wf = Wf[col];
#pragma unroll
                for (int mt = 0; mt < 4; mt++)
#pragma unroll
                    for (int r = 0; r < 4; r++) {
                        float v = (acc[mt][q][r] - mean[mt][r]) * rstd[mt][r] * gc + bc;
                        p[mt][r] += (v * sigmoidf(v)) * wf;
                    }
            }
            __syncthreads();                  // red stats reads done everywhere
#pragma unroll
            for (int mt = 0; mt < 4; mt++)
#pragma unroll
                for (int r = 0; r < 4; r++) {
                    float s = p[mt][r];
#pragma unroll
                    for (int off = 1; off < 16; off <<= 1) s += __shfl_xor(s, off, 64);
                    if (ar == 0) red[(mt * 16 + quad * 4 + r) * 8 + w] = s;
                }
            __syncthreads();
            if (t < 64) {
                float s = 0.f;
#pragma unroll
                for (int q = 0; q < 8; q++) s += red[t * 8 + q];
                logits[r0 + t] = s + bfp[0];
            }
        }
    }
}

// ---------------------------------------------------------------------------
// Top-100 per batch (sorted desc, ties -> lower index). Grid B, block 256.
// ---------------------------------------------------------------------------
__global__ __launch_bounds__(256) void topk_kernel(
    const float* __restrict__ logits, int* __restrict__ idx_out,
    float* __restrict__ out, int B)
{
    __shared__ float v[5376];
    __shared__ float wv_s[4];
    __shared__ int wi_s[4];

    const int t = threadIdx.x, b = blockIdx.x;
    const int lane = t & 63, w = t >> 6;

    for (int i = t; i < 5376; i += 256) v[i] = logits[b * 5376 + i];
    __syncthreads();

    int cnt = 0;
    for (int k = 0; k < 100; k++) {
        float bv = -1e30f;
        int bi = 0x7fffffff;
        for (int i = t; i < 5376; i += 256) {
            const float val = v[i];
            if (val > bv) { bv = val; bi = i; }
        }
#pragma unroll
        for (int off = 32; off > 0; off >>= 1) {
            const float ov = __shfl_xor(bv, off, 64);
            const int oi = __shfl_xor(bi, off, 64);
            if (ov > bv || (ov == bv && oi < bi)) { bv = ov; bi = oi; }
        }
        if (lane == 0) { wv_s[w] = bv; wi_s[w] = bi; }
        __syncthreads();
        if (t == 0) {
            float fb = wv_s[0]; int fi = wi_s[0];
            for (int q = 1; q < 4; q++)
                if (wv_s[q] > fb || (wv_s[q] == fb && wi_s[q] < fi)) { fb = wv_s[q]; fi = wi_s[q]; }
            v[fi] = -1e30f;
            idx_out[b * 100 + k] = fi;
            out[B + b * 100 + k] = sigmoidf(fb);
            if (fb > 0.0f) cnt++;
        }
        __syncthreads();
    }
    if (t == 0) out[b] = (float)cnt;
}

// ---------------------------------------------------------------------------
// fp32 GEMM+bias+LN-stats on the wave-private 32x256 LDS tile (R3 core).
// ---------------------------------------------------------------------------
__device__ __forceinline__ void gemm8_pipelined(
    const float* __restrict__ Wg, const float* __restrict__ bias,
    float* X, float (*Wbuf)[8 * 256], int t,
    float acc[8][4], float mean[8], float rstd[8])
{
    const int lane = t & 63, w = t >> 6;
#pragma unroll
    for (int mi = 0; mi < 8; mi++)
#pragma unroll
        for (int c = 0; c < 4; c++) acc[mi][c] = 0.0f;

#pragma unroll
    for (int i = 0; i < 2; i++) {
        const int q = w * 2 + i;
        async_load16(&Wg[(size_t)q * 256 + lane * 4], &Wbuf[0][q * 256]);
    }

    for (int ch = 0; ch < 32; ch++) {
        __syncthreads();
        if (ch + 1 < 32) {
#pragma unroll
            for (int i = 0; i < 2; i++) {
                const int q = w * 2 + i;
                async_load16(&Wg[(size_t)((ch + 1) * 8 + q) * 256 + lane * 4],
                             &Wbuf[(ch + 1) & 1][q * 256]);
            }
        }
        const float* Wb = Wbuf[ch & 1];
#pragma unroll
        for (int k4 = 0; k4 < 2; k4++) {
            float4 xq[8];
#pragma unroll
            for (int mi = 0; mi < 8; mi++)
                xq[mi] = *(const float4*)&X[(w * 8 + mi) * 256 + ch * 8 + k4 * 4];
#pragma unroll
            for (int j = 0; j < 4; j++) {
                const float4 wv = *(const float4*)&Wb[(k4 * 4 + j) * 256 + lane * 4];
#pragma unroll
                for (int mi = 0; mi < 8; mi++) {
                    const float xs = (j == 0) ? xq[mi].x : (j == 1) ? xq[mi].y
                                   : (j == 2) ? xq[mi].z : xq[mi].w;
                    acc[mi][0] += xs * wv.x;
                    acc[mi][1] += xs * wv.y;
                    acc[mi][2] += xs * wv.z;
                    acc[mi][3] += xs * wv.w;
                }
            }
        }
    }

    const int o = lane * 4;
    const float4 bv = *(const float4*)&bias[o];
#pragma unroll
    for (int mi = 0; mi < 8; mi++) {
        acc[mi][0] += bv.x; acc[mi][1] += bv.y; acc[mi][2] += bv.z; acc[mi][3] += bv.w;
        float s  = acc[mi][0] + acc[mi][1] + acc[mi][2] + acc[mi][3];
        float ss = acc[mi][0] * acc[mi][0] + acc[mi][1] * acc[mi][1] +
                   acc[mi][2] * acc[mi][2] + acc[mi][3] * acc[mi][3];
        s  = wave_sum(s);
        ss = wave_sum(ss);
        const float m = s * (1.0f / 256.0f);
        mean[mi] = m;
        rstd[mi] = rsqrtf(ss * (1.0f / 256.0f) - m * m + LN_EPS);
    }
}

// ---------------------------------------------------------------------------
// Fused heads (fp32, proven): gather + 4 layers + finals. Grid (25,2).
// ---------------------------------------------------------------------------
__global__ __launch_bounds__(256) void heads_mlp(
    const float* __restrict__ flat, const int* __restrict__ idxb,
    const float* __restrict__ cWs, const float* __restrict__ cbs,
    const float* __restrict__ cg, const float* __restrict__ cb,
    const float* __restrict__ cWf, const float* __restrict__ cbf,
    const float* __restrict__ xWs, const float* __restrict__ xbs,
    const float* __restrict__ xg, const float* __restrict__ xb_,
    const float* __restrict__ xWf, const float* __restrict__ xbf,
    const int* __restrict__ full_h, const int* __restrict__ full_w,
    float* __restrict__ out, int B)
{
    __shared__ float X[32 * 256];
    __shared__ float Wbuf[2][8 * 256];
    const int head = blockIdx.y;
    const float* Ws  = head ? xWs : cWs;
    const float* bsv = head ? xbs : cbs;
    const float* gv_ = head ? xg  : cg;
    const float* bv_ = head ? xb_ : cb;

    const int t = threadIdx.x, lane = t & 63, w = t >> 6;
    const int r0 = blockIdx.x * 32;

#pragma unroll
    for (int i = 0; i < 8; i++) {
        const int r = r0 + w * 8 + i;
        const int n = idxb[r];
        const int b = r / 100;
        *(float4*)&X[(w * 8 + i) * 256 + lane * 4] =
            *(const float4*)&flat[((size_t)b * 5376 + n) * 256 + lane * 4];
    }

    float acc[8][4], mean[8], rstd[8];
    for (int l = 0; l < 4; l++) {
        gemm8_pipelined(Ws + l * 65536, bsv + l * 256, X, Wbuf, t, acc, mean, rstd);
        const int o = lane * 4;
        const float4 gvv = *(const float4*)&gv_[l * 256 + o];
        const float4 bvv = *(const float4*)&bv_[l * 256 + o];
        const float gl[4] = {gvv.x, gvv.y, gvv.z, gvv.w};
        const float bl[4] = {bvv.x, bvv.y, bvv.z, bvv.w};
#pragma unroll
        for (int mi = 0; mi < 8; mi++) {
            float4 outv;
            float v0 = (acc[mi][0] - mean[mi]) * rstd[mi] * gl[0] + bl[0];
            float v1 = (acc[mi][1] - mean[mi]) * rstd[mi] * gl[1] + bl[1];
            float v2 = (acc[mi][2] - mean[mi]) * rstd[mi] * gl[2] + bl[2];
            float v3 = (acc[mi][3] - mean[mi]) * rstd[mi] * gl[3] + bl[3];
            outv.x = v0 * sigmoidf(v0); outv.y = v1 * sigmoidf(v1);
            outv.z = v2 * sigmoidf(v2); outv.w = v3 * sigmoidf(v3);
            *(float4*)&X[(w * 8 + mi) * 256 + o] = outv;
        }
    }
    __syncthreads();

    const int m = t >> 3, g = t & 7;
    if (head == 0) {
        const int jbase = g * 10;
        float lg[10];
#pragma unroll
        for (int jj = 0; jj < 10; jj++) lg[jj] = cbf[jbase + jj];
        for (int k = 0; k < 256; k++) {
            const float hv = X[m * 256 + k];
            const float* wr = &cWf[k * 80 + jbase];
#pragma unroll
            for (int jj = 0; jj < 10; jj++) lg[jj] += hv * wr[jj];
        }
        float best = lg[0]; int bj = jbase;
#pragma unroll
        for (int jj = 1; jj < 10; jj++)
            if (lg[jj] > best) { best = lg[jj]; bj = jbase + jj; }
#pragma unroll
        for (int off = 1; off < 8; off <<= 1) {
            const float ob = __shfl_xor(best, off, 64);
            const int oj = __shfl_xor(bj, off, 64);
            if (ob > best || (ob == best && oj < bj)) { best = ob; bj = oj; }
        }
        if (g == 0) out[B + B * 100 + r0 + m] = (float)bj;
    } else {
        float a[4] = {0.f, 0.f, 0.f, 0.f};
#pragma unroll
        for (int k4 = 0; k4 < 8; k4++) {
            const float4 hv = *(const float4*)&X[m * 256 + g * 32 + k4 * 4];
            const float h4[4] = {hv.x, hv.y, hv.z, hv.w};
#pragma unroll
            for (int j = 0; j < 4; j++) {
                const int k = g * 32 + k4 * 4 + j;
                const float4 wf = *(const float4*)&xWf[k * 4];
                a[0] += h4[j] * wf.x; a[1] += h4[j] * wf.y;
                a[2] += h4[j] * wf.z; a[3] += h4[j] * wf.w;
            }
        }
#pragma unroll
        for (int off = 1; off < 8; off <<= 1) {
            a[0] += __shfl_xor(a[0], off, 64);
            a[1] += __shfl_xor(a[1], off, 64);
            a[2] += __shfl_xor(a[2], off, 64);
            a[3] += __shfl_xor(a[3], off, 64);
        }
        if (g == 0) {
            const int r = r0 + m;
            const float e0 = a[0] + xbf[0], e1 = a[1] + xbf[1];
            const float e2 = a[2] + xbf[2], e3 = a[3] + xbf[3];
            const int n = idxb[r];
            int base, gw, gh;
            if (n < 4096)      { base = 0;    gw = 64; gh = 64; }
            else if (n < 5120) { base = 4096; gw = 32; gh = 32; }
            else               { base = 5120; gw = 16; gh = 16; }
            const int p = n - base;
            const int py = p / gw, px = p % gw;
            const float gx = (px + 0.5f) / gw;
            const float gy = (py + 0.5f) / gh;
            const float fw = (float)full_w[0], fh = (float)full_h[0];
            const int ob = B + 2 * B * 100;
            out[ob + r * 4 + 0] = (gx - 0.5f / gw * expf(e0)) * fw;
            out[ob + r * 4 + 1] = (gy - 0.5f / gh * expf(e1)) * fh;
            out[ob + r * 4 + 2] = (gx + 0.5f / gw * expf(e2)) * fw;
            out[ob + r * 4 + 3] = (gy + 0.5f / gh * expf(e3)) * fh;
        }
    }
}

extern "C" void kernel_launch(void* const* d_in, const int* in_sizes, int n_in,
                              void* d_out, int out_size, void* d_ws, size_t ws_size,
                              hipStream_t stream)
{
    const float* x3  = (const float*)d_in[0];
    const float* x4  = (const float*)d_in[1];
    const float* x5  = (const float*)d_in[2];
    const float* lw3 = (const float*)d_in[3];
    const float* lw4 = (const float*)d_in[4];
    const float* lw5 = (const float*)d_in[5];
    const float* bng = (const float*)d_in[6];
    const float* bnb = (const float*)d_in[7];
    const float* bnm = (const float*)d_in[8];
    const float* bnv = (const float*)d_in[9];

    const float* loc_Ws  = (const float*)d_in[10];
    const float* loc_bs  = (const float*)d_in[11];
    const float* loc_lng = (const float*)d_in[12];
    const float* loc_lnb = (const float*)d_in[13];
    const float* loc_Wf  = (const float*)d_in[14];
    const float* loc_bf  = (const float*)d_in[15];

    const float* cls_Ws  = (const float*)d_in[16];
    const float* cls_bs  = (const float*)d_in[17];
    const float* cls_lng = (const float*)d_in[18];
    const float* cls_lnb = (const float*)d_in[19];
    const float* cls_Wf  = (const float*)d_in[20];
    const float* cls_bf  = (const float*)d_in[21];

    const float* box_Ws  = (const float*)d_in[22];
    const float* box_bs  = (const float*)d_in[23];
    const float* box_lng = (const float*)d_in[24];
    const float* box_lnb = (const float*)d_in[25];
    const float* box_Wf  = (const float*)d_in[26];
    const float* box_bf  = (const float*)d_in[27];

    const int* full_h = (const int*)d_in[28];
    const int* full_w = (const int*)d_in[29];

    const int B = in_sizes[0] / (256 * 64 * 64);   // 8
    const int M = B * 5376;                        // 43008

    float* ws = (float*)d_ws;
    float* flat = ws;                                  // [M*256]
    float* loc  = flat + (size_t)M * 256;              // [M]
    int*   idxb = (int*)(loc + M);                     // [B*100] (padded 1024)
    float* Wt3  = (float*)(idxb + 1024);               // [256*256]
    float* Wt4  = Wt3 + 256 * 256;                     // [512*256]
    float* Wt5  = Wt4 + 512 * 256;                     // [1024*256]
    _Float16* locWpk = (_Float16*)(Wt5 + 1024 * 256);  // 4*8*16*2*64*8 halves = 1 MB

    float* out = (float*)d_out;
    const dim3 blk(256);

    // 0) weight preprocessing
    transpose_w<<<dim3(256 / 32, 8), blk, 0, stream>>>(lw3, Wt3, 256);
    transpose_w<<<dim3(512 / 32, 8), blk, 0, stream>>>(lw4, Wt4, 512);
    transpose_w<<<dim3(1024 / 32, 8), blk, 0, stream>>>(lw5, Wt5, 1024);
    prep_wfrag16<<<128, blk, 0, stream>>>(loc_Ws, locWpk);

    // 1) laterals -> flat
    lateral_k<32, 128, 4, 8 ><<<dim3(128, B, 2), blk, 0, stream>>>(x3, Wt3, bng + 0,   bnb + 0,   bnm + 0,   bnv + 0,   flat, 4096, 0);
    lateral_k<32, 64,  2, 16><<<dim3(32,  B, 4), blk, 0, stream>>>(x4, Wt4, bng + 256, bnb + 256, bnm + 256, bnv + 256, flat, 1024, 4096);
    lateral_k<16, 64,  1, 32><<<dim3(16,  B, 4), blk, 0, stream>>>(x5, Wt5, bng + 512, bnb + 512, bnm + 512, bnv + 512, flat, 256,  5120);

    // 2) fused loc MLP (fp16x2 MFMA) -> logits
    loc_mlp_f16<<<M / 64, dim3(512), 0, stream>>>(flat, locWpk, loc_bs,
                                                  loc_lng, loc_lnb, loc_Wf, loc_bf, loc);

    // 3) top-k
    topk_kernel<<<B, blk, 0, stream>>>(loc, idxb, out, B);

    // 4) both heads (fp32, proven)
    heads_mlp<<<dim3((B * 100) / 32, 2), blk, 0, stream>>>(
        flat, idxb,
        cls_Ws, cls_bs, cls_lng, cls_lnb, cls_Wf, cls_bf,
        box_Ws, box_bs, box_lng, box_lnb, box_Wf, box_bf,
        full_h, full_w, out, B);
}